// Round 12
// baseline (1285.194 us; speedup 1.0000x reference)
//
#include <hip/hip_runtime.h>

// Problem constants (fixed by the reference)
#define NU 100000
#define NV 50000
#define KSUP 5
#define ESUP 400000
#define NEDGE (KSUP * ESUP)   // 2,000,000
#define NE 500000
#define DIN 512
#define DGCN 500
#define FSUP 100     // DGCN / KSUP
#define DSIDE 128
#define HSIDE 64
#define DENC 128
#define NBAS 3
#define NCLS 5

#define TMPW 640     // padded tmp width: 5 supports x 128 (256B-aligned slices)
#define XW 576       // X width: 500 gcn + 64 side + 12 pad (K = 9*64)

// two-level scatter geometry
#define RU 98        // ceil(NU/1024) node ranges (U)
#define RV 49        // ceil(NV/1024) node ranges (V)
#define NBU (KSUP * RU)   // 490 U buckets
#define NBV (KSUP * RV)   // 245 V buckets
#define NBT (NBU + NBV)   // 735
#define CAPU 5120    // mean 4096, +16 sigma
#define CAPV 10240   // mean 8192, +22 sigma
#define CHUNK 8192   // edges per block in binhist

__device__ __forceinline__ ushort f2bf(float x) {
    union { float f; unsigned u; } c; c.f = x;
    unsigned r = (c.u + 0x7FFFu + ((c.u >> 16) & 1u)) >> 16;   // RNE
    return (ushort)r;
}
__device__ __forceinline__ float bf2f(ushort h) {
    union { unsigned u; float f; } c; c.u = ((unsigned)h) << 16;
    return c.f;
}
// unpack a u32 holding two bf16 (lo = even col, hi = odd col)
__device__ __forceinline__ float lof(uint g) { return __uint_as_float(g << 16); }
__device__ __forceinline__ float hif(uint g) { return __uint_as_float(g & 0xffff0000u); }

typedef __attribute__((ext_vector_type(4))) float f32x4;
typedef __attribute__((ext_vector_type(8))) short bf16x8;
typedef __attribute__((address_space(3))) void lds_void;
typedef const __attribute__((address_space(1))) void glob_void;
typedef unsigned long long ull;

// ---------------------------------------------------------------------------
// bf16 MFMA GEMM: C[M,N] = A[M,K](bf16,K-major) @ BT[N,K](bf16,K-major)^T
// 128x128 tile, BK=64, 4 waves (2x2). LDS XOR-swizzled via pre-swizzled
// global source (rule #21). Grid: x = col tile (FASTEST, so col-tiles of one
// row-panel are dispatch-adjacent -> A panel L3-reused), y = row tile.
template<int STORE_BF16>
__global__ __launch_bounds__(256) void gemm_bf16_k(
    const ushort* __restrict__ A, const ushort* __restrict__ BT,
    void* __restrict__ Cout, int M, int N, int K, int ldc)
{
    __shared__ ushort As[128 * 64];
    __shared__ ushort Bs[128 * 64];
    const int t = threadIdx.x;
    const int lane = t & 63;
    const int w = t >> 6;
    const int wr = w >> 1, wc = w & 1;
    const int rowBase = blockIdx.y * 128;
    const int colBase = blockIdx.x * 128;

    f32x4 acc[4][4] = {};

    for (int k0 = 0; k0 < K; k0 += 64) {
        #pragma unroll
        for (int i = 0; i < 4; ++i) {
            int chi = i * 256 + t;
            int r = chi >> 3;
            int c = (((chi >> 3) & 7) ^ (chi & 7)) * 8;
            int ga = rowBase + r; if (ga > M - 1) ga = M - 1;
            __builtin_amdgcn_global_load_lds(
                (glob_void*)(A + (size_t)ga * K + k0 + c),
                (lds_void*)(As + (size_t)chi * 8), 16, 0, 0);
            int gb = colBase + r; if (gb > N - 1) gb = N - 1;
            __builtin_amdgcn_global_load_lds(
                (glob_void*)(BT + (size_t)gb * K + k0 + c),
                (lds_void*)(Bs + (size_t)chi * 8), 16, 0, 0);
        }
        __syncthreads();

        #pragma unroll
        for (int kk = 0; kk < 2; ++kk) {
            bf16x8 af[4], bfr[4];
            const int cb2 = (kk * 32 + (lane >> 4) * 8) * 2;
            #pragma unroll
            for (int mi = 0; mi < 4; ++mi) {
                int r = wr * 64 + mi * 16 + (lane & 15);
                int off = (r * 128 + cb2) ^ ((r & 7) << 4);
                af[mi] = *(const bf16x8*)((const char*)As + off);
            }
            #pragma unroll
            for (int nj = 0; nj < 4; ++nj) {
                int r = wc * 64 + nj * 16 + (lane & 15);
                int off = (r * 128 + cb2) ^ ((r & 7) << 4);
                bfr[nj] = *(const bf16x8*)((const char*)Bs + off);
            }
            #pragma unroll
            for (int mi = 0; mi < 4; ++mi)
                #pragma unroll
                for (int nj = 0; nj < 4; ++nj)
                    acc[mi][nj] = __builtin_amdgcn_mfma_f32_16x16x32_bf16(
                        af[mi], bfr[nj], acc[mi][nj], 0, 0, 0);
        }
        __syncthreads();
    }

    #pragma unroll
    for (int mi = 0; mi < 4; ++mi) {
        #pragma unroll
        for (int q = 0; q < 4; ++q) {
            int gr = rowBase + wr * 64 + mi * 16 + (lane >> 4) * 4 + q;
            if (gr >= M) continue;
            #pragma unroll
            for (int nj = 0; nj < 4; ++nj) {
                int gc = colBase + wc * 64 + nj * 16 + (lane & 15);
                float v = acc[mi][nj][q];
                if (STORE_BF16)
                    ((ushort*)Cout)[(size_t)gr * ldc + gc] = f2bf(v);
                else
                    ((float*)Cout)[(size_t)gr * ldc + gc] = v;
            }
        }
    }
}

// ---------------------------------------------------------------------------
// side dense (fp32 compute): writes bf16 relu(A@B+bias) into X cols [500,564)
#define BM 64
#define BN 64
#define BK 16
__global__ __launch_bounds__(256) void gemm_side_k(
    const float* __restrict__ A, const float* __restrict__ B,
    const float* __restrict__ bias, ushort* __restrict__ X,
    int M, int K)
{
    __shared__ float As[BK][BM + 4];
    __shared__ float Bs[BK][BN + 4];
    const int t = threadIdx.x;
    const int rowBase = blockIdx.x * BM;
    const int ty = t >> 4, tx = t & 15;
    float acc[4][4] = {};

    for (int k0 = 0; k0 < K; k0 += BK) {
        #pragma unroll
        for (int p = 0; p < 4; ++p) {
            int r = p * 16 + (t >> 4), kk = t & 15;
            int gr = rowBase + r, gk = k0 + kk;
            As[kk][r] = (gr < M && gk < K) ? A[(size_t)gr * K + gk] : 0.f;
        }
        #pragma unroll
        for (int p = 0; p < 4; ++p) {
            int kk = p * 4 + (t >> 6), j = t & 63;
            int gk = k0 + kk;
            Bs[kk][j] = (j < HSIDE && gk < K) ? B[(size_t)gk * HSIDE + j] : 0.f;
        }
        __syncthreads();
        #pragma unroll
        for (int kk = 0; kk < BK; ++kk) {
            float4 a4 = *reinterpret_cast<const float4*>(&As[kk][ty * 4]);
            float4 b4 = *reinterpret_cast<const float4*>(&Bs[kk][tx * 4]);
            float aa[4] = {a4.x, a4.y, a4.z, a4.w};
            float bb[4] = {b4.x, b4.y, b4.z, b4.w};
            #pragma unroll
            for (int i = 0; i < 4; ++i)
                #pragma unroll
                for (int j = 0; j < 4; ++j)
                    acc[i][j] = fmaf(aa[i], bb[j], acc[i][j]);
        }
        __syncthreads();
    }
    #pragma unroll
    for (int i = 0; i < 4; ++i) {
        int gr = rowBase + ty * 4 + i;
        if (gr >= M) continue;
        #pragma unroll
        for (int j = 0; j < 4; ++j) {
            int gc = tx * 4 + j;
            if (gc < HSIDE)
                X[(size_t)gr * XW + 500 + gc] = f2bf(fmaxf(acc[i][j] + bias[gc], 0.f));
        }
    }
}

// ---------------------------------------------------------------------------
// conversions
__global__ __launch_bounds__(256) void cvt_k(const float* __restrict__ in,
                                             ushort* __restrict__ out, long n) {
    long i = ((long)blockIdx.x * 256 + threadIdx.x) * 4;
    if (i >= n) return;
    float4 v = *(const float4*)(in + i);
    ushort4 o;
    o.x = f2bf(v.x); o.y = f2bf(v.y); o.z = f2bf(v.z); o.w = f2bf(v.w);
    *(ushort4*)(out + i) = o;
}

// fused u/v input conversion
__global__ __launch_bounds__(256) void cvt_in_k(
    const float* __restrict__ u_in, const float* __restrict__ v_in,
    ushort* __restrict__ u_bf, ushort* __restrict__ v_bf)
{
    long i = ((long)blockIdx.x * 256 + threadIdx.x) * 4;
    const long nu = (long)NU * 512;
    const float* src; ushort* dst;
    if (i < nu) { src = u_in; dst = u_bf; }
    else {
        i -= nu;
        if (i >= (long)NV * 512) return;
        src = v_in; dst = v_bf;
    }
    float4 v = *(const float4*)(src + i);
    ushort4 o;
    o.x = f2bf(v.x); o.y = f2bf(v.y); o.z = f2bf(v.z); o.w = f2bf(v.w);
    *(ushort4*)(dst + i) = o;
}

// WencT2[n'][d], n' in [0,640): k=n'>>7, f=n'&127; val = f<100 ? W_enc[k][d][f] : 0
__global__ __launch_bounds__(256) void cvt_wencT2_k(const float* __restrict__ W,
                                                    ushort* __restrict__ out) {
    int idx = blockIdx.x * 256 + threadIdx.x;   // 640*512
    int np = idx >> 9, d = idx & 511;
    int k = np >> 7, f = np & 127;
    float v = (f < FSUP) ? W[((size_t)k * DIN + d) * FSUP + f] : 0.f;
    out[idx] = f2bf(v);
}

// W2fT[j][c] = bf16(W2[c][j]) for c<564, 0 for pad; both U and I via blockIdx.y
__global__ __launch_bounds__(256) void cvt_w2fT2_k(
    const float* __restrict__ Wu2, const float* __restrict__ Wi2,
    ushort* __restrict__ outU, ushort* __restrict__ outI)
{
    int idx = blockIdx.x * 256 + threadIdx.x;   // 128*576
    if (idx >= DENC * XW) return;
    const float* W = blockIdx.y ? Wi2 : Wu2;
    ushort* out = blockIdx.y ? outI : outU;
    int j = idx / XW, c = idx - j * XW;
    float v = (c < DGCN + HSIDE) ? W[(size_t)c * DENC + j] : 0.f;
    out[idx] = f2bf(v);
}

// ---------------------------------------------------------------------------
// Level-1 binning, contention-free: per-block LDS histogram -> ONE global
// atomicAdd per (block, bucket) to reserve a range -> LDS-cursor appends.
__global__ __launch_bounds__(256) void binhist_k(
    const int* __restrict__ su, const int* __restrict__ si,
    const float* __restrict__ sv,
    int* __restrict__ histU, int* __restrict__ histV,
    int* __restrict__ bCnt,              // [NBT] contiguous (U then V)
    ull* __restrict__ bktU, ull* __restrict__ bktV)
{
    __shared__ int lcnt[NBT];
    __shared__ int lbase[NBT];
    const int t = threadIdx.x;
    const int e0 = blockIdx.x * CHUNK;

    for (int i = t; i < NBT; i += 256) lcnt[i] = 0;
    __syncthreads();

    // pass A: LDS bucket histogram + global rowPtr histograms
    for (int i = t; i < CHUNK; i += 256) {
        int e = e0 + i;
        if (e >= NEDGE) break;
        int k = e / ESUP;
        int r = su[e], c = si[e];
        atomicAdd(&histU[k * NU + r], 1);
        atomicAdd(&histV[k * NV + c], 1);
        atomicAdd(&lcnt[k * RU + (r >> 10)], 1);
        atomicAdd(&lcnt[NBU + k * RV + (c >> 10)], 1);
    }
    __syncthreads();

    // reserve global ranges: one atomic per (block, bucket)
    for (int i = t; i < NBT; i += 256) {
        int n = lcnt[i];
        lbase[i] = n ? atomicAdd(&bCnt[i], n) : 0;
    }
    __syncthreads();
    for (int i = t; i < NBT; i += 256) lcnt[i] = 0;
    __syncthreads();

    // pass B: append via LDS cursors (normal stores -> lines merge in L2)
    for (int i = t; i < CHUNK; i += 256) {
        int e = e0 + i;
        if (e >= NEDGE) break;
        int k = e / ESUP;
        int r = su[e], c = si[e];
        ull vb = (ull)(unsigned)__float_as_int(sv[e]) << 32;
        int bu = k * RU + (r >> 10);
        int pu = lbase[bu] + atomicAdd(&lcnt[bu], 1);
        if (pu < CAPU)
            bktU[(size_t)bu * CAPU + pu] = vb | (uint)(((r & 1023) << 16) | c);
        int bv = NBU + k * RV + (c >> 10);
        int pv = lbase[bv] + atomicAdd(&lcnt[bv], 1);
        if (pv < CAPV)
            bktV[(size_t)(bv - NBU) * CAPV + pv] = vb | (uint)(((c & 1023) << 17) | r);
    }
}

__global__ __launch_bounds__(256) void scan_reduce_k(const int* __restrict__ in,
                                                     int* __restrict__ bs, int n) {
    __shared__ int sm[256];
    int base = blockIdx.x * 2048 + threadIdx.x * 8;
    int s = 0;
    #pragma unroll
    for (int i = 0; i < 8; ++i) { int idx = base + i; if (idx < n) s += in[idx]; }
    sm[threadIdx.x] = s; __syncthreads();
    for (int off = 128; off; off >>= 1) {
        if (threadIdx.x < off) sm[threadIdx.x] += sm[threadIdx.x + off];
        __syncthreads();
    }
    if (threadIdx.x == 0) bs[blockIdx.x] = sm[0];
}

__global__ __launch_bounds__(256) void scan_bs_k(int* __restrict__ bs, int nb) {
    __shared__ int sm[256];
    int t = threadIdx.x;
    int v = (t < nb) ? bs[t] : 0;
    sm[t] = v; __syncthreads();
    for (int off = 1; off < 256; off <<= 1) {
        int add = (t >= off) ? sm[t - off] : 0;
        __syncthreads();
        sm[t] += add;
        __syncthreads();
    }
    if (t < nb) bs[t] = sm[t] - v;   // exclusive
}

__global__ __launch_bounds__(256) void scan_write_k(const int* __restrict__ in,
                                                    const int* __restrict__ bs,
                                                    int* __restrict__ out,
                                                    int* __restrict__ pos, int n) {
    __shared__ int sm[256];
    int t = threadIdx.x;
    int base = blockIdx.x * 2048 + t * 8;
    int loc[8]; int s = 0;
    #pragma unroll
    for (int i = 0; i < 8; ++i) {
        int idx = base + i;
        loc[i] = (idx < n) ? in[idx] : 0;
        s += loc[i];
    }
    sm[t] = s; __syncthreads();
    int sv = s;
    for (int off = 1; off < 256; off <<= 1) {
        int add = (t >= off) ? sm[t - off] : 0;
        __syncthreads();
        sm[t] += add;
        __syncthreads();
    }
    int thOff = bs[blockIdx.x] + sm[t] - sv;
    int run = 0;
    #pragma unroll
    for (int i = 0; i < 8; ++i) {
        int idx = base + i;
        if (idx < n) { int v = thOff + run; out[idx] = v; pos[idx] = v; }
        run += loc[i];
    }
    if (blockIdx.x == 0 && t == 0) out[n] = NEDGE;   // sentinel (padded buffer)
}

// Level-2 scatter: one block per bucket; NT src reads keep the stream out of
// cache; destination window ~32-64KB -> L2-resident full-line writebacks.
__global__ __launch_bounds__(256) void scat2_k(
    const int* __restrict__ bCnt,
    const ull* __restrict__ bktU, const ull* __restrict__ bktV,
    int* __restrict__ posU, int* __restrict__ posV,
    ull* __restrict__ eU, ull* __restrict__ eV)
{
    int b = blockIdx.x;
    if (b < NBU) {
        int k = b / RU, baseR = (b % RU) << 10;
        int cnt = bCnt[b]; if (cnt > CAPU) cnt = CAPU;
        const ull* src = bktU + (size_t)b * CAPU;
        for (int i = threadIdx.x; i < cnt; i += 256) {
            ull en = __builtin_nontemporal_load(&src[i]);
            uint w0 = (uint)en;
            int c = w0 & 0xFFFF;
            int r = baseR + (int)(w0 >> 16);
            int p = atomicAdd(&posU[k * NU + r], 1);
            __builtin_nontemporal_store((en & 0xFFFFFFFF00000000ull) |
                                        (uint)(c * (TMPW * 2)), &eU[p]);
        }
    } else {
        int bb = b - NBU;
        int k = bb / RV, baseC = (bb % RV) << 10;
        int cnt = bCnt[b]; if (cnt > CAPV) cnt = CAPV;
        const ull* src = bktV + (size_t)bb * CAPV;
        for (int i = threadIdx.x; i < cnt; i += 256) {
            ull en = __builtin_nontemporal_load(&src[i]);
            uint w0 = (uint)en;
            int r = w0 & 0x1FFFF;
            int c = baseC + (int)(w0 >> 17);
            int p = atomicAdd(&posV[k * NV + c], 1);
            __builtin_nontemporal_store((en & 0xFFFFFFFF00000000ull) |
                                        (uint)(r * (TMPW * 2)), &eV[p]);
        }
    }
}

// ---------------------------------------------------------------------------
// Merged-support CSR aggregation helper: ONE wave per node, supports
// [K0,K0+NK) in one interleaved latency chain. NT edge loads (stream-once).
template<int K0, int NK, int B, int NNODE>
__device__ __forceinline__ void agg_do(
    const int* __restrict__ rowPtr, const ull* __restrict__ eArr,
    const char* __restrict__ tSrc, int n, uint lane4,
    float* __restrict__ a0, float* __restrict__ a1)
{
    int s[NK], d[NK];
    #pragma unroll
    for (int kk = 0; kk < NK; ++kk) {
        int g = (K0 + kk) * NNODE + n;
        int ss = rowPtr[g];
        int ee = rowPtr[g + 1];     // sentinel covers the last segment
        s[kk] = ss; d[kk] = ee - ss;
    }
    uint ex[NK][B], ev[NK][B], gw[NK][B];
    #pragma unroll
    for (int kk = 0; kk < NK; ++kk)
        #pragma unroll
        for (int i = 0; i < B; ++i) {
            int idx = (i < d[kk]) ? i : 0;
            ull t = __builtin_nontemporal_load(&eArr[s[kk] + idx]);
            ex[kk][i] = (i < d[kk]) ? (uint)t : 0u;
            ev[kk][i] = (uint)(t >> 32);
        }
    #pragma unroll
    for (int kk = 0; kk < NK; ++kk)
        #pragma unroll
        for (int i = 0; i < B; ++i)
            gw[kk][i] = *(const uint*)(tSrc + (ex[kk][i] + lane4 + ((uint)(K0 + kk) << 8)));
    #pragma unroll
    for (int kk = 0; kk < NK; ++kk) {
        float x0 = 0.f, x1 = 0.f;
        #pragma unroll
        for (int i = 0; i < B; ++i)
            if (i < d[kk]) {
                float v = __uint_as_float(ev[kk][i]);
                x0 = fmaf(v, lof(gw[kk][i]), x0);
                x1 = fmaf(v, hif(gw[kk][i]), x1);
            }
        a0[K0 + kk] = x0; a1[K0 + kk] = x1;
    }
    #pragma unroll
    for (int kk = 0; kk < NK; ++kk) {
        if (d[kk] > B) {            // wave-uniform branch
            uint fx[B], fv[B], g1[B];
            #pragma unroll
            for (int i = 0; i < B; ++i) {
                int idx = (B + i < d[kk]) ? B + i : B;
                ull t = __builtin_nontemporal_load(&eArr[s[kk] + idx]);
                fx[i] = (B + i < d[kk]) ? (uint)t : 0u;
                fv[i] = (uint)(t >> 32);
            }
            #pragma unroll
            for (int i = 0; i < B; ++i)
                g1[i] = *(const uint*)(tSrc + (fx[i] + lane4 + ((uint)(K0 + kk) << 8)));
            #pragma unroll
            for (int i = 0; i < B; ++i)
                if (B + i < d[kk]) {
                    float v = __uint_as_float(fv[i]);
                    a0[K0 + kk] = fmaf(v, lof(g1[i]), a0[K0 + kk]);
                    a1[K0 + kk] = fmaf(v, hif(g1[i]), a1[K0 + kk]);
                }
            for (int p = 2 * B; p < d[kk]; ++p) {
                ull t = __builtin_nontemporal_load(&eArr[s[kk] + p]);
                uint g = *(const uint*)(tSrc + ((uint)t + lane4 + ((uint)(K0 + kk) << 8)));
                float v = __uint_as_float((uint)(t >> 32));
                a0[K0 + kk] = fmaf(v, lof(g), a0[K0 + kk]);
                a1[K0 + kk] = fmaf(v, hif(g), a1[K0 + kk]);
            }
        }
    }
}

__device__ __forceinline__ void agg_store(ushort* Xrow, int lane,
                                          const float* a0, const float* a1) {
    #pragma unroll
    for (int k = 0; k < KSUP; ++k) {
        uint payload = (uint)f2bf(fmaxf(a0[k], 0.f)) |
                       ((uint)f2bf(fmaxf(a1[k], 0.f)) << 16);
        if (lane < 50)
            __builtin_nontemporal_store(payload, (uint*)(Xrow + k * FSUP) + lane);
    }
    if (lane < 6)
        __builtin_nontemporal_store(0u, (uint*)(Xrow + 564) + lane);
}

// U-direction: gathers tmpV (64 MB, L3-resident during this kernel)
__global__ __launch_bounds__(256) void agg_u_k(
    const int* __restrict__ rowPtrU, const ull* __restrict__ eU,
    const ushort* __restrict__ tmpV, ushort* __restrict__ Xu)
{
    const int lane = threadIdx.x & 63;
    const int n = blockIdx.x * 4 + (threadIdx.x >> 6);
    const uint lane4 = (uint)(((lane < 50) ? lane : 49) << 2);
    float a0[KSUP], a1[KSUP];
    agg_do<0, KSUP, 4, NU>(rowPtrU, eU, (const char*)tmpV, n, lane4, a0, a1);
    agg_store(Xu + (size_t)n * XW, lane, a0, a1);
}

// V-direction: gathers tmpU (128 MB, L3-resident during this kernel)
__global__ __launch_bounds__(256) void agg_v_k(
    const int* __restrict__ rowPtrV, const ull* __restrict__ eV,
    const ushort* __restrict__ tmpU, ushort* __restrict__ Xv)
{
    const int lane = threadIdx.x & 63;
    const int n = blockIdx.x * 4 + (threadIdx.x >> 6);
    const uint lane4 = (uint)(((lane < 50) ? lane : 49) << 2);
    float a0[KSUP], a1[KSUP];
    agg_do<0, 3, 8, NV>(rowPtrV, eV, (const char*)tmpU, n, lane4, a0, a1);
    agg_do<3, 2, 8, NV>(rowPtrV, eV, (const char*)tmpU, n, lane4, a0, a1);
    agg_store(Xv + (size_t)n * XW, lane, a0, a1);
}

// ---------------------------------------------------------------------------
// final decoder: int2 gathers; basis[b] = dot(embU[u], Vb[v][b]); out=basis@cls
__global__ __launch_bounds__(256) void dec_k(
    const int* __restrict__ ue, const int* __restrict__ ie,
    const ushort* __restrict__ embU, const ushort* __restrict__ Vb,
    const float* __restrict__ cls, float* __restrict__ out, int nE)
{
    int e = blockIdx.x * 8 + (threadIdx.x >> 5);
    if (e >= nE) return;
    int lane = threadIdx.x & 31;
    int u = ue[e], v = ie[e];
    const int2* pu2 = (const int2*)(embU + (size_t)u * DENC);        // 32 int2
    const int2* pv2 = (const int2*)(Vb + (size_t)v * (NBAS * DENC)); // 96 int2
    int2 uu = pu2[lane];                 // cols 4l..4l+3
    int2 bb[NBAS];
    #pragma unroll
    for (int b = 0; b < NBAS; ++b) bb[b] = pv2[b * 32 + lane];
    float uxl = lof((uint)uu.x), uxh = hif((uint)uu.x);
    float uyl = lof((uint)uu.y), uyh = hif((uint)uu.y);
    float s[NBAS];
    #pragma unroll
    for (int b = 0; b < NBAS; ++b) {
        float t = lof((uint)bb[b].x) * uxl;
        t = fmaf(hif((uint)bb[b].x), uxh, t);
        t = fmaf(lof((uint)bb[b].y), uyl, t);
        s[b] = fmaf(hif((uint)bb[b].y), uyh, t);
    }
    #pragma unroll
    for (int off = 16; off; off >>= 1)
        #pragma unroll
        for (int b = 0; b < NBAS; ++b) s[b] += __shfl_xor(s[b], off, 32);
    if (lane < NCLS) {
        float o = 0.f;
        #pragma unroll
        for (int b = 0; b < NBAS; ++b) o += s[b] * cls[b * NCLS + lane];
        out[(size_t)e * NCLS + lane] = o;
    }
}

// ---------------------------------------------------------------------------
extern "C" void kernel_launch(void* const* d_in, const int* in_sizes, int n_in,
                              void* d_out, int out_size, void* d_ws, size_t ws_size,
                              hipStream_t stream) {
    const int*   sup_u  = (const int*)  d_in[0];
    const int*   sup_i  = (const int*)  d_in[1];
    const float* sup_v  = (const float*)d_in[2];
    const float* u_in   = (const float*)d_in[3];
    const float* v_in   = (const float*)d_in[4];
    const float* u_side = (const float*)d_in[5];
    const float* v_side = (const float*)d_in[6];
    const int*   ue     = (const int*)  d_in[7];
    const int*   ie     = (const int*)  d_in[8];
    const float* W_enc  = (const float*)d_in[9];
    const float* Wu1    = (const float*)d_in[10];
    const float* bu1    = (const float*)d_in[11];
    const float* Wi1    = (const float*)d_in[12];
    const float* bi1    = (const float*)d_in[13];
    const float* Wu2    = (const float*)d_in[14];
    const float* Wi2    = (const float*)d_in[15];
    const float* dec_W  = (const float*)d_in[16];
    const float* deccls = (const float*)d_in[17];

    char* ws = (char*)d_ws;
    ushort* u_bf   = (ushort*)(ws);
    ushort* v_bf   = (ushort*)(ws + 102400000LL);
    ushort* Xu     = (ushort*)(ws);
    ushort* Xv     = (ushort*)(ws + 115200000LL);
    // CSR @176M (dead after agg); rowPtr regions padded for the +1 sentinel.
    int*    histU  = (int*)(ws + 176000000LL);          // [5][NU] 2M
    int*    histV  = (int*)(ws + 178000000LL);          // [5][NV] 1M
    int*    rowPtrU= (int*)(ws + 179000000LL);          // 2M + 4 sentinel
    int*    rowPtrV= (int*)(ws + 181200000LL);          // 1M + 4 sentinel
    int*    posU   = (int*)(ws + 182400000LL);          // 2M
    int*    posV   = (int*)(ws + 184600000LL);          // 1M
    int*    bsums  = (int*)(ws + 185800000LL);          // 4KB
    int*    bCnt   = (int*)(ws + 185810000LL);          // [735] contiguous
    ull*    eU     = (ull*)(ws + 186000000LL);          // [2M] 16M
    ull*    eV     = (ull*)(ws + 202000000LL);          // [2M] 16M ends 218M
    // tmp @220M (dead after agg): tmpU [NU][640] 128M, tmpV [NV][640] 64M
    ushort* tmpU   = (ushort*)(ws + 220000000LL);
    ushort* tmpV   = (ushort*)(ws + 348000000LL);       // ends 412M
    // L1 buckets: overlay on tmp region (dead before encoder GEMMs write tmp)
    ull*    bktU   = (ull*)(ws + 220000000LL);          // 490*5120*8  = 20.1M
    ull*    bktV   = (ull*)(ws + 241000000LL);          // 245*10240*8 = 20.1M
    // post-agg overlays:
    ushort* embUbf = (ushort*)(ws + 176000000LL);       // [NU][128] 25.6M (over CSR)
    ushort* embVbf = (ushort*)(ws + 202000000LL);       // [NV][128] 12.8M (over eV)
    ushort* Vb     = (ushort*)(ws + 220000000LL);       // [NV][384] 38.4M (over tmp)
    // weights @412M:
    ushort* WencT2 = (ushort*)(ws + 412000000LL);       // [640][512] 0.66M
    ushort* W2ufT  = (ushort*)(ws + 413000000LL);       // [128][576] 0.15M
    ushort* W2ifT  = (ushort*)(ws + 413200000LL);       // [128][576] 0.15M
    ushort* decbf  = (ushort*)(ws + 413400000LL);       // [384][128] 0.10M

    dim3 blk(256);
    const int gu128 = (NU + 127) / 128;   // 782
    const int gv128 = (NV + 127) / 128;   // 391
    const int gu64  = (NU + 63) / 64;     // 1563
    const int gv64  = (NV + 63) / 64;     // 782
    const int gB    = (NEDGE + CHUNK - 1) / CHUNK;   // 245

    // ---- phase 1: bf16 conversions + CSR build (two-level scatter) ----
    cvt_in_k<<<dim3((NU + NV) * 512 / 4 / 256), blk, 0, stream>>>(u_in, v_in, u_bf, v_bf);
    cvt_wencT2_k<<<dim3(TMPW * 512 / 256), blk, 0, stream>>>(W_enc, WencT2);
    cvt_w2fT2_k<<<dim3((DENC * XW + 255) / 256, 2), blk, 0, stream>>>(Wu2, Wi2, W2ufT, W2ifT);
    cvt_k<<<dim3((NBAS * DENC * DENC / 4 + 255) / 256), blk, 0, stream>>>(
        dec_W, decbf, (long)NBAS * DENC * DENC);

    hipMemsetAsync(histU, 0, 3000000LL, stream);        // histU + histV
    hipMemsetAsync(bCnt, 0, 4096, stream);              // bucket counters
    binhist_k<<<dim3(gB), blk, 0, stream>>>(sup_u, sup_i, sup_v,
                                            histU, histV, bCnt, bktU, bktV);
    scan_reduce_k<<<dim3(245), blk, 0, stream>>>(histU, bsums, KSUP * NU);
    scan_bs_k<<<dim3(1), blk, 0, stream>>>(bsums, 245);
    scan_write_k<<<dim3(245), blk, 0, stream>>>(histU, bsums, rowPtrU, posU, KSUP * NU);
    scan_reduce_k<<<dim3(123), blk, 0, stream>>>(histV, bsums, KSUP * NV);
    scan_bs_k<<<dim3(1), blk, 0, stream>>>(bsums, 123);
    scan_write_k<<<dim3(123), blk, 0, stream>>>(histV, bsums, rowPtrV, posV, KSUP * NV);
    scat2_k<<<dim3(NBT), blk, 0, stream>>>(bCnt, bktU, bktV, posU, posV, eU, eV);

    // ---- phase 2: encoder GEMMs (col tile = x fastest -> A panel L3-reuse) ----
    gemm_bf16_k<1><<<dim3(TMPW / 128, gu128), blk, 0, stream>>>(
        u_bf, WencT2, tmpU, NU, TMPW, 512, TMPW);
    gemm_bf16_k<1><<<dim3(TMPW / 128, gv128), blk, 0, stream>>>(
        v_bf, WencT2, tmpV, NV, TMPW, 512, TMPW);

    // ---- phase 3: CSR aggregation, U then V (each gather table L3-fits) ----
    agg_u_k<<<dim3(NU / 4), blk, 0, stream>>>(rowPtrU, eU, tmpV, Xu);
    agg_v_k<<<dim3(NV / 4), blk, 0, stream>>>(rowPtrV, eV, tmpU, Xv);

    // ---- phase 4: side dense -> X cols 500..563 (bf16) ----
    gemm_side_k<<<dim3(gu64), blk, 0, stream>>>(u_side, Wu1, bu1, Xu, NU, DSIDE);
    gemm_side_k<<<dim3(gv64), blk, 0, stream>>>(v_side, Wi1, bi1, Xv, NV, DSIDE);

    // ---- phase 5: dense2 = X @ W2fT (K=576) -> emb bf16 ----
    gemm_bf16_k<1><<<dim3(1, gu128), blk, 0, stream>>>(Xu, W2ufT, embUbf, NU, 128, XW, 128);
    gemm_bf16_k<1><<<dim3(1, gv128), blk, 0, stream>>>(Xv, W2ifT, embVbf, NV, 128, XW, 128);

    // ---- phase 6: decoder precompute on V side: Vb = embV @ decbf^T ----
    gemm_bf16_k<1><<<dim3(3, gv128), blk, 0, stream>>>(embVbf, decbf, Vb, NV, 384, 128, 384);

    // ---- phase 7: final decoder over edges ----
    dec_k<<<dim3(NE / 8), blk, 0, stream>>>(ue, ie, embUbf, Vb, deccls, (float*)d_out, NE);
}

// Round 13
// 1251.192 us; speedup vs baseline: 1.0272x; 1.0272x over previous
//
#include <hip/hip_runtime.h>

// Problem constants (fixed by the reference)
#define NU 100000
#define NV 50000
#define KSUP 5
#define ESUP 400000
#define NEDGE (KSUP * ESUP)   // 2,000,000
#define NE 500000
#define DIN 512
#define DGCN 500
#define FSUP 100     // DGCN / KSUP
#define DSIDE 128
#define HSIDE 64
#define DENC 128
#define NBAS 3
#define NCLS 5

#define TMPW 640     // padded tmp width: 5 supports x 128 (256B-aligned slices)
#define XW 576       // X width: 500 gcn + 64 side + 12 pad (K = 9*64)

// two-level scatter geometry
#define RU 98        // ceil(NU/1024) node ranges (U)
#define RV 49        // ceil(NV/1024) node ranges (V)
#define NBU (KSUP * RU)   // 490 U buckets
#define NBV (KSUP * RV)   // 245 V buckets
#define NBT (NBU + NBV)   // 735
#define CAPU 5120    // mean 4096, +16 sigma
#define CAPV 10240   // mean 8192, +22 sigma
#define CHUNK 8192   // edges per block in binhist
#define SPLIT 4      // blocks per bucket in scat2

__device__ __forceinline__ ushort f2bf(float x) {
    union { float f; unsigned u; } c; c.f = x;
    unsigned r = (c.u + 0x7FFFu + ((c.u >> 16) & 1u)) >> 16;   // RNE
    return (ushort)r;
}
__device__ __forceinline__ float bf2f(ushort h) {
    union { unsigned u; float f; } c; c.u = ((unsigned)h) << 16;
    return c.f;
}
// unpack a u32 holding two bf16 (lo = even col, hi = odd col)
__device__ __forceinline__ float lof(uint g) { return __uint_as_float(g << 16); }
__device__ __forceinline__ float hif(uint g) { return __uint_as_float(g & 0xffff0000u); }

typedef __attribute__((ext_vector_type(4))) float f32x4;
typedef __attribute__((ext_vector_type(8))) short bf16x8;
typedef __attribute__((address_space(3))) void lds_void;
typedef const __attribute__((address_space(1))) void glob_void;
typedef unsigned long long ull;

// ---------------------------------------------------------------------------
// bf16 MFMA GEMM: C[M,N] = A[M,K](bf16,K-major) @ BT[N,K](bf16,K-major)^T
// 128x128 tile, BK=64, 4 waves (2x2). LDS XOR-swizzled via pre-swizzled
// global source (rule #21). Grid: x = col tile (fastest -> A panel L3-reuse),
// y = row tile.
template<int STORE_BF16>
__global__ __launch_bounds__(256) void gemm_bf16_k(
    const ushort* __restrict__ A, const ushort* __restrict__ BT,
    void* __restrict__ Cout, int M, int N, int K, int ldc)
{
    __shared__ ushort As[128 * 64];
    __shared__ ushort Bs[128 * 64];
    const int t = threadIdx.x;
    const int lane = t & 63;
    const int w = t >> 6;
    const int wr = w >> 1, wc = w & 1;
    const int rowBase = blockIdx.y * 128;
    const int colBase = blockIdx.x * 128;

    f32x4 acc[4][4] = {};

    for (int k0 = 0; k0 < K; k0 += 64) {
        #pragma unroll
        for (int i = 0; i < 4; ++i) {
            int chi = i * 256 + t;
            int r = chi >> 3;
            int c = (((chi >> 3) & 7) ^ (chi & 7)) * 8;
            int ga = rowBase + r; if (ga > M - 1) ga = M - 1;
            __builtin_amdgcn_global_load_lds(
                (glob_void*)(A + (size_t)ga * K + k0 + c),
                (lds_void*)(As + (size_t)chi * 8), 16, 0, 0);
            int gb = colBase + r; if (gb > N - 1) gb = N - 1;
            __builtin_amdgcn_global_load_lds(
                (glob_void*)(BT + (size_t)gb * K + k0 + c),
                (lds_void*)(Bs + (size_t)chi * 8), 16, 0, 0);
        }
        __syncthreads();

        #pragma unroll
        for (int kk = 0; kk < 2; ++kk) {
            bf16x8 af[4], bfr[4];
            const int cb2 = (kk * 32 + (lane >> 4) * 8) * 2;
            #pragma unroll
            for (int mi = 0; mi < 4; ++mi) {
                int r = wr * 64 + mi * 16 + (lane & 15);
                int off = (r * 128 + cb2) ^ ((r & 7) << 4);
                af[mi] = *(const bf16x8*)((const char*)As + off);
            }
            #pragma unroll
            for (int nj = 0; nj < 4; ++nj) {
                int r = wc * 64 + nj * 16 + (lane & 15);
                int off = (r * 128 + cb2) ^ ((r & 7) << 4);
                bfr[nj] = *(const bf16x8*)((const char*)Bs + off);
            }
            #pragma unroll
            for (int mi = 0; mi < 4; ++mi)
                #pragma unroll
                for (int nj = 0; nj < 4; ++nj)
                    acc[mi][nj] = __builtin_amdgcn_mfma_f32_16x16x32_bf16(
                        af[mi], bfr[nj], acc[mi][nj], 0, 0, 0);
        }
        __syncthreads();
    }

    #pragma unroll
    for (int mi = 0; mi < 4; ++mi) {
        #pragma unroll
        for (int q = 0; q < 4; ++q) {
            int gr = rowBase + wr * 64 + mi * 16 + (lane >> 4) * 4 + q;
            if (gr >= M) continue;
            #pragma unroll
            for (int nj = 0; nj < 4; ++nj) {
                int gc = colBase + wc * 64 + nj * 16 + (lane & 15);
                float v = acc[mi][nj][q];
                if (STORE_BF16)
                    ((ushort*)Cout)[(size_t)gr * ldc + gc] = f2bf(v);
                else
                    ((float*)Cout)[(size_t)gr * ldc + gc] = v;
            }
        }
    }
}

// ---------------------------------------------------------------------------
// side dense (fp32 compute): writes bf16 relu(A@B+bias) into X cols [500,564)
#define BM 64
#define BN 64
#define BK 16
__global__ __launch_bounds__(256) void gemm_side_k(
    const float* __restrict__ A, const float* __restrict__ B,
    const float* __restrict__ bias, ushort* __restrict__ X,
    int M, int K)
{
    __shared__ float As[BK][BM + 4];
    __shared__ float Bs[BK][BN + 4];
    const int t = threadIdx.x;
    const int rowBase = blockIdx.x * BM;
    const int ty = t >> 4, tx = t & 15;
    float acc[4][4] = {};

    for (int k0 = 0; k0 < K; k0 += BK) {
        #pragma unroll
        for (int p = 0; p < 4; ++p) {
            int r = p * 16 + (t >> 4), kk = t & 15;
            int gr = rowBase + r, gk = k0 + kk;
            As[kk][r] = (gr < M && gk < K) ? A[(size_t)gr * K + gk] : 0.f;
        }
        #pragma unroll
        for (int p = 0; p < 4; ++p) {
            int kk = p * 4 + (t >> 6), j = t & 63;
            int gk = k0 + kk;
            Bs[kk][j] = (j < HSIDE && gk < K) ? B[(size_t)gk * HSIDE + j] : 0.f;
        }
        __syncthreads();
        #pragma unroll
        for (int kk = 0; kk < BK; ++kk) {
            float4 a4 = *reinterpret_cast<const float4*>(&As[kk][ty * 4]);
            float4 b4 = *reinterpret_cast<const float4*>(&Bs[kk][tx * 4]);
            float aa[4] = {a4.x, a4.y, a4.z, a4.w};
            float bb[4] = {b4.x, b4.y, b4.z, b4.w};
            #pragma unroll
            for (int i = 0; i < 4; ++i)
                #pragma unroll
                for (int j = 0; j < 4; ++j)
                    acc[i][j] = fmaf(aa[i], bb[j], acc[i][j]);
        }
        __syncthreads();
    }
    #pragma unroll
    for (int i = 0; i < 4; ++i) {
        int gr = rowBase + ty * 4 + i;
        if (gr >= M) continue;
        #pragma unroll
        for (int j = 0; j < 4; ++j) {
            int gc = tx * 4 + j;
            if (gc < HSIDE)
                X[(size_t)gr * XW + 500 + gc] = f2bf(fmaxf(acc[i][j] + bias[gc], 0.f));
        }
    }
}

// ---------------------------------------------------------------------------
// conversions
__global__ __launch_bounds__(256) void cvt_k(const float* __restrict__ in,
                                             ushort* __restrict__ out, long n) {
    long i = ((long)blockIdx.x * 256 + threadIdx.x) * 4;
    if (i >= n) return;
    float4 v = *(const float4*)(in + i);
    ushort4 o;
    o.x = f2bf(v.x); o.y = f2bf(v.y); o.z = f2bf(v.z); o.w = f2bf(v.w);
    *(ushort4*)(out + i) = o;
}

// fused u/v input conversion
__global__ __launch_bounds__(256) void cvt_in_k(
    const float* __restrict__ u_in, const float* __restrict__ v_in,
    ushort* __restrict__ u_bf, ushort* __restrict__ v_bf)
{
    long i = ((long)blockIdx.x * 256 + threadIdx.x) * 4;
    const long nu = (long)NU * 512;
    const float* src; ushort* dst;
    if (i < nu) { src = u_in; dst = u_bf; }
    else {
        i -= nu;
        if (i >= (long)NV * 512) return;
        src = v_in; dst = v_bf;
    }
    float4 v = *(const float4*)(src + i);
    ushort4 o;
    o.x = f2bf(v.x); o.y = f2bf(v.y); o.z = f2bf(v.z); o.w = f2bf(v.w);
    *(ushort4*)(dst + i) = o;
}

// WencT2[n'][d], n' in [0,640): k=n'>>7, f=n'&127; val = f<100 ? W_enc[k][d][f] : 0
__global__ __launch_bounds__(256) void cvt_wencT2_k(const float* __restrict__ W,
                                                    ushort* __restrict__ out) {
    int idx = blockIdx.x * 256 + threadIdx.x;   // 640*512
    int np = idx >> 9, d = idx & 511;
    int k = np >> 7, f = np & 127;
    float v = (f < FSUP) ? W[((size_t)k * DIN + d) * FSUP + f] : 0.f;
    out[idx] = f2bf(v);
}

// W2fT[j][c] = bf16(W2[c][j]) for c<564, 0 for pad; both U and I via blockIdx.y
__global__ __launch_bounds__(256) void cvt_w2fT2_k(
    const float* __restrict__ Wu2, const float* __restrict__ Wi2,
    ushort* __restrict__ outU, ushort* __restrict__ outI)
{
    int idx = blockIdx.x * 256 + threadIdx.x;   // 128*576
    if (idx >= DENC * XW) return;
    const float* W = blockIdx.y ? Wi2 : Wu2;
    ushort* out = blockIdx.y ? outI : outU;
    int j = idx / XW, c = idx - j * XW;
    float v = (c < DGCN + HSIDE) ? W[(size_t)c * DENC + j] : 0.f;
    out[idx] = f2bf(v);
}

// ---------------------------------------------------------------------------
// Level-1 binning, contention-free: per-block LDS histogram -> ONE global
// atomicAdd per (block, bucket) to reserve a range -> LDS-cursor appends.
__global__ __launch_bounds__(256) void binhist_k(
    const int* __restrict__ su, const int* __restrict__ si,
    const float* __restrict__ sv,
    int* __restrict__ histU, int* __restrict__ histV,
    int* __restrict__ bCnt,              // [NBT] contiguous (U then V)
    ull* __restrict__ bktU, ull* __restrict__ bktV)
{
    __shared__ int lcnt[NBT];
    __shared__ int lbase[NBT];
    const int t = threadIdx.x;
    const int e0 = blockIdx.x * CHUNK;

    for (int i = t; i < NBT; i += 256) lcnt[i] = 0;
    __syncthreads();

    // pass A: LDS bucket histogram + global rowPtr histograms
    for (int i = t; i < CHUNK; i += 256) {
        int e = e0 + i;
        if (e >= NEDGE) break;
        int k = e / ESUP;
        int r = su[e], c = si[e];
        atomicAdd(&histU[k * NU + r], 1);
        atomicAdd(&histV[k * NV + c], 1);
        atomicAdd(&lcnt[k * RU + (r >> 10)], 1);
        atomicAdd(&lcnt[NBU + k * RV + (c >> 10)], 1);
    }
    __syncthreads();

    // reserve global ranges: one atomic per (block, bucket)
    for (int i = t; i < NBT; i += 256) {
        int n = lcnt[i];
        lbase[i] = n ? atomicAdd(&bCnt[i], n) : 0;
    }
    __syncthreads();
    for (int i = t; i < NBT; i += 256) lcnt[i] = 0;
    __syncthreads();

    // pass B: append via LDS cursors (plain stores -> lines merge in L2)
    for (int i = t; i < CHUNK; i += 256) {
        int e = e0 + i;
        if (e >= NEDGE) break;
        int k = e / ESUP;
        int r = su[e], c = si[e];
        ull vb = (ull)(unsigned)__float_as_int(sv[e]) << 32;
        int bu = k * RU + (r >> 10);
        int pu = lbase[bu] + atomicAdd(&lcnt[bu], 1);
        if (pu < CAPU)
            bktU[(size_t)bu * CAPU + pu] = vb | (uint)(((r & 1023) << 16) | c);
        int bv = NBU + k * RV + (c >> 10);
        int pv = lbase[bv] + atomicAdd(&lcnt[bv], 1);
        if (pv < CAPV)
            bktV[(size_t)(bv - NBU) * CAPV + pv] = vb | (uint)(((c & 1023) << 17) | r);
    }
}

__global__ __launch_bounds__(256) void scan_reduce_k(const int* __restrict__ in,
                                                     int* __restrict__ bs, int n) {
    __shared__ int sm[256];
    int base = blockIdx.x * 2048 + threadIdx.x * 8;
    int s = 0;
    #pragma unroll
    for (int i = 0; i < 8; ++i) { int idx = base + i; if (idx < n) s += in[idx]; }
    sm[threadIdx.x] = s; __syncthreads();
    for (int off = 128; off; off >>= 1) {
        if (threadIdx.x < off) sm[threadIdx.x] += sm[threadIdx.x + off];
        __syncthreads();
    }
    if (threadIdx.x == 0) bs[blockIdx.x] = sm[0];
}

__global__ __launch_bounds__(256) void scan_bs_k(int* __restrict__ bs, int nb) {
    __shared__ int sm[256];
    int t = threadIdx.x;
    int v = (t < nb) ? bs[t] : 0;
    sm[t] = v; __syncthreads();
    for (int off = 1; off < 256; off <<= 1) {
        int add = (t >= off) ? sm[t - off] : 0;
        __syncthreads();
        sm[t] += add;
        __syncthreads();
    }
    if (t < nb) bs[t] = sm[t] - v;   // exclusive
}

__global__ __launch_bounds__(256) void scan_write_k(const int* __restrict__ in,
                                                    const int* __restrict__ bs,
                                                    int* __restrict__ out,
                                                    int* __restrict__ pos, int n) {
    __shared__ int sm[256];
    int t = threadIdx.x;
    int base = blockIdx.x * 2048 + t * 8;
    int loc[8]; int s = 0;
    #pragma unroll
    for (int i = 0; i < 8; ++i) {
        int idx = base + i;
        loc[i] = (idx < n) ? in[idx] : 0;
        s += loc[i];
    }
    sm[t] = s; __syncthreads();
    int sv = s;
    for (int off = 1; off < 256; off <<= 1) {
        int add = (t >= off) ? sm[t - off] : 0;
        __syncthreads();
        sm[t] += add;
        __syncthreads();
    }
    int thOff = bs[blockIdx.x] + sm[t] - sv;
    int run = 0;
    #pragma unroll
    for (int i = 0; i < 8; ++i) {
        int idx = base + i;
        if (idx < n) { int v = thOff + run; out[idx] = v; pos[idx] = v; }
        run += loc[i];
    }
    if (blockIdx.x == 0 && t == 0) out[n] = NEDGE;   // sentinel (padded buffer)
}

// Level-2 scatter: SPLIT blocks per bucket (grid.y = part). NT loads on the
// streamed bucket source; PLAIN stores on the destination so the ~32-64KB
// L2-resident window merges 8B writes into full lines (R12 bug: NT dest
// stores bypassed merging -> 281 MB writebacks for a 32 MB payload).
__global__ __launch_bounds__(256) void scat2_k(
    const int* __restrict__ bCnt,
    const ull* __restrict__ bktU, const ull* __restrict__ bktV,
    int* __restrict__ posU, int* __restrict__ posV,
    ull* __restrict__ eU, ull* __restrict__ eV)
{
    int b = blockIdx.x;
    int start = blockIdx.y * 256 + threadIdx.x;
    const int stride = 256 * SPLIT;
    if (b < NBU) {
        int k = b / RU, baseR = (b % RU) << 10;
        int cnt = bCnt[b]; if (cnt > CAPU) cnt = CAPU;
        const ull* src = bktU + (size_t)b * CAPU;
        for (int i = start; i < cnt; i += stride) {
            ull en = __builtin_nontemporal_load(&src[i]);
            uint w0 = (uint)en;
            int c = w0 & 0xFFFF;
            int r = baseR + (int)(w0 >> 16);
            int p = atomicAdd(&posU[k * NU + r], 1);
            eU[p] = (en & 0xFFFFFFFF00000000ull) | (uint)(c * (TMPW * 2));
        }
    } else {
        int bb = b - NBU;
        int k = bb / RV, baseC = (bb % RV) << 10;
        int cnt = bCnt[b]; if (cnt > CAPV) cnt = CAPV;
        const ull* src = bktV + (size_t)bb * CAPV;
        for (int i = start; i < cnt; i += stride) {
            ull en = __builtin_nontemporal_load(&src[i]);
            uint w0 = (uint)en;
            int r = w0 & 0x1FFFF;
            int c = baseC + (int)(w0 >> 17);
            int p = atomicAdd(&posV[k * NV + c], 1);
            eV[p] = (en & 0xFFFFFFFF00000000ull) | (uint)(r * (TMPW * 2));
        }
    }
}

// ---------------------------------------------------------------------------
// Merged-support CSR aggregation helper: ONE wave per node, supports
// [K0,K0+NK) in one interleaved latency chain. NT edge loads (stream-once).
template<int K0, int NK, int B, int NNODE>
__device__ __forceinline__ void agg_do(
    const int* __restrict__ rowPtr, const ull* __restrict__ eArr,
    const char* __restrict__ tSrc, int n, uint lane4,
    float* __restrict__ a0, float* __restrict__ a1)
{
    int s[NK], d[NK];
    #pragma unroll
    for (int kk = 0; kk < NK; ++kk) {
        int g = (K0 + kk) * NNODE + n;
        int ss = rowPtr[g];
        int ee = rowPtr[g + 1];     // sentinel covers the last segment
        s[kk] = ss; d[kk] = ee - ss;
    }
    uint ex[NK][B], ev[NK][B], gw[NK][B];
    #pragma unroll
    for (int kk = 0; kk < NK; ++kk)
        #pragma unroll
        for (int i = 0; i < B; ++i) {
            int idx = (i < d[kk]) ? i : 0;
            ull t = __builtin_nontemporal_load(&eArr[s[kk] + idx]);
            ex[kk][i] = (i < d[kk]) ? (uint)t : 0u;
            ev[kk][i] = (uint)(t >> 32);
        }
    #pragma unroll
    for (int kk = 0; kk < NK; ++kk)
        #pragma unroll
        for (int i = 0; i < B; ++i)
            gw[kk][i] = *(const uint*)(tSrc + (ex[kk][i] + lane4 + ((uint)(K0 + kk) << 8)));
    #pragma unroll
    for (int kk = 0; kk < NK; ++kk) {
        float x0 = 0.f, x1 = 0.f;
        #pragma unroll
        for (int i = 0; i < B; ++i)
            if (i < d[kk]) {
                float v = __uint_as_float(ev[kk][i]);
                x0 = fmaf(v, lof(gw[kk][i]), x0);
                x1 = fmaf(v, hif(gw[kk][i]), x1);
            }
        a0[K0 + kk] = x0; a1[K0 + kk] = x1;
    }
    #pragma unroll
    for (int kk = 0; kk < NK; ++kk) {
        if (d[kk] > B) {            // wave-uniform branch
            uint fx[B], fv[B], g1[B];
            #pragma unroll
            for (int i = 0; i < B; ++i) {
                int idx = (B + i < d[kk]) ? B + i : B;
                ull t = __builtin_nontemporal_load(&eArr[s[kk] + idx]);
                fx[i] = (B + i < d[kk]) ? (uint)t : 0u;
                fv[i] = (uint)(t >> 32);
            }
            #pragma unroll
            for (int i = 0; i < B; ++i)
                g1[i] = *(const uint*)(tSrc + (fx[i] + lane4 + ((uint)(K0 + kk) << 8)));
            #pragma unroll
            for (int i = 0; i < B; ++i)
                if (B + i < d[kk]) {
                    float v = __uint_as_float(fv[i]);
                    a0[K0 + kk] = fmaf(v, lof(g1[i]), a0[K0 + kk]);
                    a1[K0 + kk] = fmaf(v, hif(g1[i]), a1[K0 + kk]);
                }
            for (int p = 2 * B; p < d[kk]; ++p) {
                ull t = __builtin_nontemporal_load(&eArr[s[kk] + p]);
                uint g = *(const uint*)(tSrc + ((uint)t + lane4 + ((uint)(K0 + kk) << 8)));
                float v = __uint_as_float((uint)(t >> 32));
                a0[K0 + kk] = fmaf(v, lof(g), a0[K0 + kk]);
                a1[K0 + kk] = fmaf(v, hif(g), a1[K0 + kk]);
            }
        }
    }
}

__device__ __forceinline__ void agg_store(ushort* Xrow, int lane,
                                          const float* a0, const float* a1) {
    #pragma unroll
    for (int k = 0; k < KSUP; ++k) {
        uint payload = (uint)f2bf(fmaxf(a0[k], 0.f)) |
                       ((uint)f2bf(fmaxf(a1[k], 0.f)) << 16);
        if (lane < 50)
            __builtin_nontemporal_store(payload, (uint*)(Xrow + k * FSUP) + lane);
    }
    if (lane < 6)
        __builtin_nontemporal_store(0u, (uint*)(Xrow + 564) + lane);
}

// U-direction: gathers tmpV (64 MB, L3-resident during this kernel)
__global__ __launch_bounds__(256) void agg_u_k(
    const int* __restrict__ rowPtrU, const ull* __restrict__ eU,
    const ushort* __restrict__ tmpV, ushort* __restrict__ Xu)
{
    const int lane = threadIdx.x & 63;
    const int n = blockIdx.x * 4 + (threadIdx.x >> 6);
    const uint lane4 = (uint)(((lane < 50) ? lane : 49) << 2);
    float a0[KSUP], a1[KSUP];
    agg_do<0, KSUP, 4, NU>(rowPtrU, eU, (const char*)tmpV, n, lane4, a0, a1);
    agg_store(Xu + (size_t)n * XW, lane, a0, a1);
}

// V-direction: gathers tmpU (128 MB, L3-resident during this kernel)
__global__ __launch_bounds__(256) void agg_v_k(
    const int* __restrict__ rowPtrV, const ull* __restrict__ eV,
    const ushort* __restrict__ tmpU, ushort* __restrict__ Xv)
{
    const int lane = threadIdx.x & 63;
    const int n = blockIdx.x * 4 + (threadIdx.x >> 6);
    const uint lane4 = (uint)(((lane < 50) ? lane : 49) << 2);
    float a0[KSUP], a1[KSUP];
    agg_do<0, 3, 8, NV>(rowPtrV, eV, (const char*)tmpU, n, lane4, a0, a1);
    agg_do<3, 2, 8, NV>(rowPtrV, eV, (const char*)tmpU, n, lane4, a0, a1);
    agg_store(Xv + (size_t)n * XW, lane, a0, a1);
}

// ---------------------------------------------------------------------------
// final decoder: int2 gathers; basis[b] = dot(embU[u], Vb[v][b]); out=basis@cls
__global__ __launch_bounds__(256) void dec_k(
    const int* __restrict__ ue, const int* __restrict__ ie,
    const ushort* __restrict__ embU, const ushort* __restrict__ Vb,
    const float* __restrict__ cls, float* __restrict__ out, int nE)
{
    int e = blockIdx.x * 8 + (threadIdx.x >> 5);
    if (e >= nE) return;
    int lane = threadIdx.x & 31;
    int u = ue[e], v = ie[e];
    const int2* pu2 = (const int2*)(embU + (size_t)u * DENC);        // 32 int2
    const int2* pv2 = (const int2*)(Vb + (size_t)v * (NBAS * DENC)); // 96 int2
    int2 uu = pu2[lane];                 // cols 4l..4l+3
    int2 bb[NBAS];
    #pragma unroll
    for (int b = 0; b < NBAS; ++b) bb[b] = pv2[b * 32 + lane];
    float uxl = lof((uint)uu.x), uxh = hif((uint)uu.x);
    float uyl = lof((uint)uu.y), uyh = hif((uint)uu.y);
    float s[NBAS];
    #pragma unroll
    for (int b = 0; b < NBAS; ++b) {
        float t = lof((uint)bb[b].x) * uxl;
        t = fmaf(hif((uint)bb[b].x), uxh, t);
        t = fmaf(lof((uint)bb[b].y), uyl, t);
        s[b] = fmaf(hif((uint)bb[b].y), uyh, t);
    }
    #pragma unroll
    for (int off = 16; off; off >>= 1)
        #pragma unroll
        for (int b = 0; b < NBAS; ++b) s[b] += __shfl_xor(s[b], off, 32);
    if (lane < NCLS) {
        float o = 0.f;
        #pragma unroll
        for (int b = 0; b < NBAS; ++b) o += s[b] * cls[b * NCLS + lane];
        out[(size_t)e * NCLS + lane] = o;
    }
}

// ---------------------------------------------------------------------------
extern "C" void kernel_launch(void* const* d_in, const int* in_sizes, int n_in,
                              void* d_out, int out_size, void* d_ws, size_t ws_size,
                              hipStream_t stream) {
    const int*   sup_u  = (const int*)  d_in[0];
    const int*   sup_i  = (const int*)  d_in[1];
    const float* sup_v  = (const float*)d_in[2];
    const float* u_in   = (const float*)d_in[3];
    const float* v_in   = (const float*)d_in[4];
    const float* u_side = (const float*)d_in[5];
    const float* v_side = (const float*)d_in[6];
    const int*   ue     = (const int*)  d_in[7];
    const int*   ie     = (const int*)  d_in[8];
    const float* W_enc  = (const float*)d_in[9];
    const float* Wu1    = (const float*)d_in[10];
    const float* bu1    = (const float*)d_in[11];
    const float* Wi1    = (const float*)d_in[12];
    const float* bi1    = (const float*)d_in[13];
    const float* Wu2    = (const float*)d_in[14];
    const float* Wi2    = (const float*)d_in[15];
    const float* dec_W  = (const float*)d_in[16];
    const float* deccls = (const float*)d_in[17];

    char* ws = (char*)d_ws;
    ushort* u_bf   = (ushort*)(ws);
    ushort* v_bf   = (ushort*)(ws + 102400000LL);
    ushort* Xu     = (ushort*)(ws);
    ushort* Xv     = (ushort*)(ws + 115200000LL);
    // CSR @176M (dead after agg); rowPtr regions padded for the +1 sentinel.
    int*    histU  = (int*)(ws + 176000000LL);          // [5][NU] 2M
    int*    histV  = (int*)(ws + 178000000LL);          // [5][NV] 1M
    int*    rowPtrU= (int*)(ws + 179000000LL);          // 2M + 4 sentinel
    int*    rowPtrV= (int*)(ws + 181200000LL);          // 1M + 4 sentinel
    int*    posU   = (int*)(ws + 182400000LL);          // 2M
    int*    posV   = (int*)(ws + 184600000LL);          // 1M
    int*    bsums  = (int*)(ws + 185800000LL);          // 4KB
    int*    bCnt   = (int*)(ws + 185810000LL);          // [735] contiguous
    ull*    eU     = (ull*)(ws + 186000000LL);          // [2M] 16M
    ull*    eV     = (ull*)(ws + 202000000LL);          // [2M] 16M ends 218M
    // tmp @220M (dead after agg): tmpU [NU][640] 128M, tmpV [NV][640] 64M
    ushort* tmpU   = (ushort*)(ws + 220000000LL);
    ushort* tmpV   = (ushort*)(ws + 348000000LL);       // ends 412M
    // L1 buckets: overlay on tmp region (dead before encoder GEMMs write tmp)
    ull*    bktU   = (ull*)(ws + 220000000LL);          // 490*5120*8  = 20.1M
    ull*    bktV   = (ull*)(ws + 241000000LL);          // 245*10240*8 = 20.1M
    // post-agg overlays:
    ushort* embUbf = (ushort*)(ws + 176000000LL);       // [NU][128] 25.6M (over CSR)
    ushort* embVbf = (ushort*)(ws + 202000000LL);       // [NV][128] 12.8M (over eV)
    ushort* Vb     = (ushort*)(ws + 220000000LL);       // [NV][384] 38.4M (over tmp)
    // weights @412M:
    ushort* WencT2 = (ushort*)(ws + 412000000LL);       // [640][512] 0.66M
    ushort* W2ufT  = (ushort*)(ws + 413000000LL);       // [128][576] 0.15M
    ushort* W2ifT  = (ushort*)(ws + 413200000LL);       // [128][576] 0.15M
    ushort* decbf  = (ushort*)(ws + 413400000LL);       // [384][128] 0.10M

    dim3 blk(256);
    const int gu128 = (NU + 127) / 128;   // 782
    const int gv128 = (NV + 127) / 128;   // 391
    const int gu64  = (NU + 63) / 64;     // 1563
    const int gv64  = (NV + 63) / 64;     // 782
    const int gB    = (NEDGE + CHUNK - 1) / CHUNK;   // 245

    // ---- phase 1: bf16 conversions + CSR build (two-level scatter) ----
    cvt_in_k<<<dim3((NU + NV) * 512 / 4 / 256), blk, 0, stream>>>(u_in, v_in, u_bf, v_bf);
    cvt_wencT2_k<<<dim3(TMPW * 512 / 256), blk, 0, stream>>>(W_enc, WencT2);
    cvt_w2fT2_k<<<dim3((DENC * XW + 255) / 256, 2), blk, 0, stream>>>(Wu2, Wi2, W2ufT, W2ifT);
    cvt_k<<<dim3((NBAS * DENC * DENC / 4 + 255) / 256), blk, 0, stream>>>(
        dec_W, decbf, (long)NBAS * DENC * DENC);

    hipMemsetAsync(histU, 0, 3000000LL, stream);        // histU + histV
    hipMemsetAsync(bCnt, 0, 4096, stream);              // bucket counters
    binhist_k<<<dim3(gB), blk, 0, stream>>>(sup_u, sup_i, sup_v,
                                            histU, histV, bCnt, bktU, bktV);
    scan_reduce_k<<<dim3(245), blk, 0, stream>>>(histU, bsums, KSUP * NU);
    scan_bs_k<<<dim3(1), blk, 0, stream>>>(bsums, 245);
    scan_write_k<<<dim3(245), blk, 0, stream>>>(histU, bsums, rowPtrU, posU, KSUP * NU);
    scan_reduce_k<<<dim3(123), blk, 0, stream>>>(histV, bsums, KSUP * NV);
    scan_bs_k<<<dim3(1), blk, 0, stream>>>(bsums, 123);
    scan_write_k<<<dim3(123), blk, 0, stream>>>(histV, bsums, rowPtrV, posV, KSUP * NV);
    scat2_k<<<dim3(NBT, SPLIT), blk, 0, stream>>>(bCnt, bktU, bktV, posU, posV, eU, eV);

    // ---- phase 2: encoder GEMMs (col tile = x fastest -> A panel L3-reuse) ----
    gemm_bf16_k<1><<<dim3(TMPW / 128, gu128), blk, 0, stream>>>(
        u_bf, WencT2, tmpU, NU, TMPW, 512, TMPW);
    gemm_bf16_k<1><<<dim3(TMPW / 128, gv128), blk, 0, stream>>>(
        v_bf, WencT2, tmpV, NV, TMPW, 512, TMPW);

    // ---- phase 3: CSR aggregation, U then V (each gather table L3-fits) ----
    agg_u_k<<<dim3(NU / 4), blk, 0, stream>>>(rowPtrU, eU, tmpV, Xu);
    agg_v_k<<<dim3(NV / 4), blk, 0, stream>>>(rowPtrV, eV, tmpU, Xv);

    // ---- phase 4: side dense -> X cols 500..563 (bf16) ----
    gemm_side_k<<<dim3(gu64), blk, 0, stream>>>(u_side, Wu1, bu1, Xu, NU, DSIDE);
    gemm_side_k<<<dim3(gv64), blk, 0, stream>>>(v_side, Wi1, bi1, Xv, NV, DSIDE);

    // ---- phase 5: dense2 = X @ W2fT (K=576) -> emb bf16 ----
    gemm_bf16_k<1><<<dim3(1, gu128), blk, 0, stream>>>(Xu, W2ufT, embUbf, NU, 128, XW, 128);
    gemm_bf16_k<1><<<dim3(1, gv128), blk, 0, stream>>>(Xv, W2ifT, embVbf, NV, 128, XW, 128);

    // ---- phase 6: decoder precompute on V side: Vb = embV @ decbf^T ----
    gemm_bf16_k<1><<<dim3(3, gv128), blk, 0, stream>>>(embVbf, decbf, Vb, NV, 384, 128, 384);

    // ---- phase 7: final decoder over edges ----
    dec_k<<<dim3(NE / 8), blk, 0, stream>>>(ue, ie, embUbf, Vb, deccls, (float*)d_out, NE);
}

// Round 14
// 1080.597 us; speedup vs baseline: 1.1893x; 1.1579x over previous
//
#include <hip/hip_runtime.h>

// Problem constants (fixed by the reference)
#define NU 100000
#define NV 50000
#define KSUP 5
#define ESUP 400000
#define NEDGE (KSUP * ESUP)   // 2,000,000
#define NE 500000
#define DIN 512
#define DGCN 500
#define FSUP 100     // DGCN / KSUP
#define DSIDE 128
#define HSIDE 64
#define DENC 128
#define NBAS 3
#define NCLS 5

#define TMPW 640     // padded tmp width: 5 supports x 128 (256B-aligned slices)
#define XW 576       // X width: 500 gcn + 64 side + 12 pad (K = 9*64)

// two-level scatter geometry (node-range = 512 so V-bucket stages in LDS)
#define BNODE 512
#define RU 196       // ceil(NU/512)
#define RV 98        // ceil(NV/512)
#define NBU (KSUP * RU)   // 980 U buckets
#define NBV (KSUP * RV)   // 490 V buckets
#define NBT (NBU + NBV)   // 1470
#define CAPU 2560    // mean 2048, +11 sigma
#define CAPV 5120    // mean 4096, +16 sigma
#define CHUNK 8192   // edges per block in binhist

__device__ __forceinline__ ushort f2bf(float x) {
    union { float f; unsigned u; } c; c.f = x;
    unsigned r = (c.u + 0x7FFFu + ((c.u >> 16) & 1u)) >> 16;   // RNE
    return (ushort)r;
}
__device__ __forceinline__ float bf2f(ushort h) {
    union { unsigned u; float f; } c; c.u = ((unsigned)h) << 16;
    return c.f;
}
// unpack a u32 holding two bf16 (lo = even col, hi = odd col)
__device__ __forceinline__ float lof(uint g) { return __uint_as_float(g << 16); }
__device__ __forceinline__ float hif(uint g) { return __uint_as_float(g & 0xffff0000u); }

typedef __attribute__((ext_vector_type(4))) float f32x4;
typedef __attribute__((ext_vector_type(8))) short bf16x8;
typedef __attribute__((address_space(3))) void lds_void;
typedef const __attribute__((address_space(1))) void glob_void;
typedef unsigned long long ull;

// ---------------------------------------------------------------------------
// bf16 MFMA GEMM: C[M,N] = A[M,K](bf16,K-major) @ BT[N,K](bf16,K-major)^T
// 128x128 tile, BK=64, 4 waves (2x2). LDS XOR-swizzled via pre-swizzled
// global source (rule #21). Grid: x = col tile (fastest -> A panel L3-reuse),
// y = row tile.
template<int STORE_BF16>
__global__ __launch_bounds__(256) void gemm_bf16_k(
    const ushort* __restrict__ A, const ushort* __restrict__ BT,
    void* __restrict__ Cout, int M, int N, int K, int ldc)
{
    __shared__ ushort As[128 * 64];
    __shared__ ushort Bs[128 * 64];
    const int t = threadIdx.x;
    const int lane = t & 63;
    const int w = t >> 6;
    const int wr = w >> 1, wc = w & 1;
    const int rowBase = blockIdx.y * 128;
    const int colBase = blockIdx.x * 128;

    f32x4 acc[4][4] = {};

    for (int k0 = 0; k0 < K; k0 += 64) {
        #pragma unroll
        for (int i = 0; i < 4; ++i) {
            int chi = i * 256 + t;
            int r = chi >> 3;
            int c = (((chi >> 3) & 7) ^ (chi & 7)) * 8;
            int ga = rowBase + r; if (ga > M - 1) ga = M - 1;
            __builtin_amdgcn_global_load_lds(
                (glob_void*)(A + (size_t)ga * K + k0 + c),
                (lds_void*)(As + (size_t)chi * 8), 16, 0, 0);
            int gb = colBase + r; if (gb > N - 1) gb = N - 1;
            __builtin_amdgcn_global_load_lds(
                (glob_void*)(BT + (size_t)gb * K + k0 + c),
                (lds_void*)(Bs + (size_t)chi * 8), 16, 0, 0);
        }
        __syncthreads();

        #pragma unroll
        for (int kk = 0; kk < 2; ++kk) {
            bf16x8 af[4], bfr[4];
            const int cb2 = (kk * 32 + (lane >> 4) * 8) * 2;
            #pragma unroll
            for (int mi = 0; mi < 4; ++mi) {
                int r = wr * 64 + mi * 16 + (lane & 15);
                int off = (r * 128 + cb2) ^ ((r & 7) << 4);
                af[mi] = *(const bf16x8*)((const char*)As + off);
            }
            #pragma unroll
            for (int nj = 0; nj < 4; ++nj) {
                int r = wc * 64 + nj * 16 + (lane & 15);
                int off = (r * 128 + cb2) ^ ((r & 7) << 4);
                bfr[nj] = *(const bf16x8*)((const char*)Bs + off);
            }
            #pragma unroll
            for (int mi = 0; mi < 4; ++mi)
                #pragma unroll
                for (int nj = 0; nj < 4; ++nj)
                    acc[mi][nj] = __builtin_amdgcn_mfma_f32_16x16x32_bf16(
                        af[mi], bfr[nj], acc[mi][nj], 0, 0, 0);
        }
        __syncthreads();
    }

    #pragma unroll
    for (int mi = 0; mi < 4; ++mi) {
        #pragma unroll
        for (int q = 0; q < 4; ++q) {
            int gr = rowBase + wr * 64 + mi * 16 + (lane >> 4) * 4 + q;
            if (gr >= M) continue;
            #pragma unroll
            for (int nj = 0; nj < 4; ++nj) {
                int gc = colBase + wc * 64 + nj * 16 + (lane & 15);
                float v = acc[mi][nj][q];
                if (STORE_BF16)
                    ((ushort*)Cout)[(size_t)gr * ldc + gc] = f2bf(v);
                else
                    ((float*)Cout)[(size_t)gr * ldc + gc] = v;
            }
        }
    }
}

// ---------------------------------------------------------------------------
// side dense (fp32 compute): writes bf16 relu(A@B+bias) into X cols [500,564)
#define BM 64
#define BN 64
#define BK 16
__global__ __launch_bounds__(256) void gemm_side_k(
    const float* __restrict__ A, const float* __restrict__ B,
    const float* __restrict__ bias, ushort* __restrict__ X,
    int M, int K)
{
    __shared__ float As[BK][BM + 4];
    __shared__ float Bs[BK][BN + 4];
    const int t = threadIdx.x;
    const int rowBase = blockIdx.x * BM;
    const int ty = t >> 4, tx = t & 15;
    float acc[4][4] = {};

    for (int k0 = 0; k0 < K; k0 += BK) {
        #pragma unroll
        for (int p = 0; p < 4; ++p) {
            int r = p * 16 + (t >> 4), kk = t & 15;
            int gr = rowBase + r, gk = k0 + kk;
            As[kk][r] = (gr < M && gk < K) ? A[(size_t)gr * K + gk] : 0.f;
        }
        #pragma unroll
        for (int p = 0; p < 4; ++p) {
            int kk = p * 4 + (t >> 6), j = t & 63;
            int gk = k0 + kk;
            Bs[kk][j] = (j < HSIDE && gk < K) ? B[(size_t)gk * HSIDE + j] : 0.f;
        }
        __syncthreads();
        #pragma unroll
        for (int kk = 0; kk < BK; ++kk) {
            float4 a4 = *reinterpret_cast<const float4*>(&As[kk][ty * 4]);
            float4 b4 = *reinterpret_cast<const float4*>(&Bs[kk][tx * 4]);
            float aa[4] = {a4.x, a4.y, a4.z, a4.w};
            float bb[4] = {b4.x, b4.y, b4.z, b4.w};
            #pragma unroll
            for (int i = 0; i < 4; ++i)
                #pragma unroll
                for (int j = 0; j < 4; ++j)
                    acc[i][j] = fmaf(aa[i], bb[j], acc[i][j]);
        }
        __syncthreads();
    }
    #pragma unroll
    for (int i = 0; i < 4; ++i) {
        int gr = rowBase + ty * 4 + i;
        if (gr >= M) continue;
        #pragma unroll
        for (int j = 0; j < 4; ++j) {
            int gc = tx * 4 + j;
            if (gc < HSIDE)
                X[(size_t)gr * XW + 500 + gc] = f2bf(fmaxf(acc[i][j] + bias[gc], 0.f));
        }
    }
}

// ---------------------------------------------------------------------------
// conversions
__global__ __launch_bounds__(256) void cvt_k(const float* __restrict__ in,
                                             ushort* __restrict__ out, long n) {
    long i = ((long)blockIdx.x * 256 + threadIdx.x) * 4;
    if (i >= n) return;
    float4 v = *(const float4*)(in + i);
    ushort4 o;
    o.x = f2bf(v.x); o.y = f2bf(v.y); o.z = f2bf(v.z); o.w = f2bf(v.w);
    *(ushort4*)(out + i) = o;
}

// fused u/v input conversion
__global__ __launch_bounds__(256) void cvt_in_k(
    const float* __restrict__ u_in, const float* __restrict__ v_in,
    ushort* __restrict__ u_bf, ushort* __restrict__ v_bf)
{
    long i = ((long)blockIdx.x * 256 + threadIdx.x) * 4;
    const long nu = (long)NU * 512;
    const float* src; ushort* dst;
    if (i < nu) { src = u_in; dst = u_bf; }
    else {
        i -= nu;
        if (i >= (long)NV * 512) return;
        src = v_in; dst = v_bf;
    }
    float4 v = *(const float4*)(src + i);
    ushort4 o;
    o.x = f2bf(v.x); o.y = f2bf(v.y); o.z = f2bf(v.z); o.w = f2bf(v.w);
    *(ushort4*)(dst + i) = o;
}

// WencT2[n'][d], n' in [0,640): k=n'>>7, f=n'&127; val = f<100 ? W_enc[k][d][f] : 0
__global__ __launch_bounds__(256) void cvt_wencT2_k(const float* __restrict__ W,
                                                    ushort* __restrict__ out) {
    int idx = blockIdx.x * 256 + threadIdx.x;   // 640*512
    int np = idx >> 9, d = idx & 511;
    int k = np >> 7, f = np & 127;
    float v = (f < FSUP) ? W[((size_t)k * DIN + d) * FSUP + f] : 0.f;
    out[idx] = f2bf(v);
}

// W2fT[j][c] = bf16(W2[c][j]) for c<564, 0 for pad; both U and I via blockIdx.y
__global__ __launch_bounds__(256) void cvt_w2fT2_k(
    const float* __restrict__ Wu2, const float* __restrict__ Wi2,
    ushort* __restrict__ outU, ushort* __restrict__ outI)
{
    int idx = blockIdx.x * 256 + threadIdx.x;   // 128*576
    if (idx >= DENC * XW) return;
    const float* W = blockIdx.y ? Wi2 : Wu2;
    ushort* out = blockIdx.y ? outI : outU;
    int j = idx / XW, c = idx - j * XW;
    float v = (c < DGCN + HSIDE) ? W[(size_t)c * DENC + j] : 0.f;
    out[idx] = f2bf(v);
}

// ---------------------------------------------------------------------------
// Level-1 binning, contention-free: per-block LDS histogram -> ONE global
// atomicAdd per (block, bucket) to reserve a range -> LDS-cursor appends.
// Entry (8B): U: w0=(r_local<<16)|c; V: w0=(c_local<<17)|r; w1=val bits.
__global__ __launch_bounds__(256) void binhist_k(
    const int* __restrict__ su, const int* __restrict__ si,
    const float* __restrict__ sv,
    int* __restrict__ histU, int* __restrict__ histV,
    int* __restrict__ bCnt,              // [NBT] contiguous (U then V)
    ull* __restrict__ bktU, ull* __restrict__ bktV)
{
    __shared__ int lcnt[NBT];
    __shared__ int lbase[NBT];
    const int t = threadIdx.x;
    const int e0 = blockIdx.x * CHUNK;

    for (int i = t; i < NBT; i += 256) lcnt[i] = 0;
    __syncthreads();

    // pass A: LDS bucket histogram + global rowPtr histograms
    for (int i = t; i < CHUNK; i += 256) {
        int e = e0 + i;
        if (e >= NEDGE) break;
        int k = e / ESUP;
        int r = su[e], c = si[e];
        atomicAdd(&histU[k * NU + r], 1);
        atomicAdd(&histV[k * NV + c], 1);
        atomicAdd(&lcnt[k * RU + (r >> 9)], 1);
        atomicAdd(&lcnt[NBU + k * RV + (c >> 9)], 1);
    }
    __syncthreads();

    // reserve global ranges: one atomic per (block, bucket)
    for (int i = t; i < NBT; i += 256) {
        int n = lcnt[i];
        lbase[i] = n ? atomicAdd(&bCnt[i], n) : 0;
    }
    __syncthreads();
    for (int i = t; i < NBT; i += 256) lcnt[i] = 0;
    __syncthreads();

    // pass B: append via LDS cursors (plain stores -> short sequential runs)
    for (int i = t; i < CHUNK; i += 256) {
        int e = e0 + i;
        if (e >= NEDGE) break;
        int k = e / ESUP;
        int r = su[e], c = si[e];
        ull vb = (ull)(unsigned)__float_as_int(sv[e]) << 32;
        int bu = k * RU + (r >> 9);
        int pu = lbase[bu] + atomicAdd(&lcnt[bu], 1);
        if (pu < CAPU)
            bktU[(size_t)bu * CAPU + pu] = vb | (uint)(((r & 511) << 16) | c);
        int bv = NBU + k * RV + (c >> 9);
        int pv = lbase[bv] + atomicAdd(&lcnt[bv], 1);
        if (pv < CAPV)
            bktV[(size_t)(bv - NBU) * CAPV + pv] = vb | (uint)(((c & 511) << 17) | r);
    }
}

__global__ __launch_bounds__(256) void scan_reduce_k(const int* __restrict__ in,
                                                     int* __restrict__ bs, int n) {
    __shared__ int sm[256];
    int base = blockIdx.x * 2048 + threadIdx.x * 8;
    int s = 0;
    #pragma unroll
    for (int i = 0; i < 8; ++i) { int idx = base + i; if (idx < n) s += in[idx]; }
    sm[threadIdx.x] = s; __syncthreads();
    for (int off = 128; off; off >>= 1) {
        if (threadIdx.x < off) sm[threadIdx.x] += sm[threadIdx.x + off];
        __syncthreads();
    }
    if (threadIdx.x == 0) bs[blockIdx.x] = sm[0];
}

__global__ __launch_bounds__(256) void scan_bs_k(int* __restrict__ bs, int nb) {
    __shared__ int sm[256];
    int t = threadIdx.x;
    int v = (t < nb) ? bs[t] : 0;
    sm[t] = v; __syncthreads();
    for (int off = 1; off < 256; off <<= 1) {
        int add = (t >= off) ? sm[t - off] : 0;
        __syncthreads();
        sm[t] += add;
        __syncthreads();
    }
    if (t < nb) bs[t] = sm[t] - v;   // exclusive
}

__global__ __launch_bounds__(256) void scan_write_k(const int* __restrict__ in,
                                                    const int* __restrict__ bs,
                                                    int* __restrict__ out, int n) {
    __shared__ int sm[256];
    int t = threadIdx.x;
    int base = blockIdx.x * 2048 + t * 8;
    int loc[8]; int s = 0;
    #pragma unroll
    for (int i = 0; i < 8; ++i) {
        int idx = base + i;
        loc[i] = (idx < n) ? in[idx] : 0;
        s += loc[i];
    }
    sm[t] = s; __syncthreads();
    int sv = s;
    for (int off = 1; off < 256; off <<= 1) {
        int add = (t >= off) ? sm[t - off] : 0;
        __syncthreads();
        sm[t] += add;
        __syncthreads();
    }
    int thOff = bs[blockIdx.x] + sm[t] - sv;
    int run = 0;
    #pragma unroll
    for (int i = 0; i < 8; ++i) {
        int idx = base + i;
        if (idx < n) out[idx] = thOff + run;
        run += loc[i];
    }
    if (blockIdx.x == 0 && t == 0) out[n] = NEDGE;   // sentinel (padded buffer)
}

// ---------------------------------------------------------------------------
// Level-2: in-bucket LDS COUNTING SORT -> fully sequential CSR writes.
// Bucket (k, 512-node range) maps to a CONTIGUOUS CSR range; in-bucket
// per-node scan reproduces rowPtr offsets exactly (no pos arrays, no dest
// atomics). Writeout is coalesced streaming -> no write amplification
// (R12/R13 bug: scattered 8B dest writes from many XCDs never merged).
__global__ __launch_bounds__(256) void scat3_k(
    const int* __restrict__ bCnt,
    const ull* __restrict__ bktU, const ull* __restrict__ bktV,
    const int* __restrict__ rowPtrU, const int* __restrict__ rowPtrV,
    ull* __restrict__ eU, ull* __restrict__ eV)
{
    __shared__ ull stage[CAPV];          // 40 KB
    __shared__ int cnt[BNODE];           // 2 KB (hist -> cursors)
    __shared__ int part[256];
    const int t = threadIdx.x;
    const int b = blockIdx.x;
    const int isU = (b < NBU);
    const ull* src;
    int n, k, baseN;
    if (isU) {
        k = b / RU; baseN = (b % RU) << 9;
        src = bktU + (size_t)b * CAPU;
        n = bCnt[b]; if (n > CAPU) n = CAPU;
    } else {
        int bb = b - NBU;
        k = bb / RV; baseN = (bb % RV) << 9;
        src = bktV + (size_t)bb * CAPV;
        n = bCnt[b]; if (n > CAPV) n = CAPV;
    }

    for (int i = t; i < BNODE; i += 256) cnt[i] = 0;
    __syncthreads();

    // pass A: histogram by local node
    for (int i = t; i < n; i += 256) {
        ull en = __builtin_nontemporal_load(&src[i]);
        uint w0 = (uint)en;
        int local = isU ? (int)(w0 >> 16) : (int)(w0 >> 17);
        atomicAdd(&cnt[local], 1);
    }
    __syncthreads();

    // block exclusive scan of 512 counters (thread t owns 2t, 2t+1)
    int c0 = cnt[2 * t], c1 = cnt[2 * t + 1];
    int s = c0 + c1;
    part[t] = s;
    __syncthreads();
    for (int off = 1; off < 256; off <<= 1) {
        int add = (t >= off) ? part[t - off] : 0;
        __syncthreads();
        part[t] += add;
        __syncthreads();
    }
    int excl = part[t] - s;
    cnt[2 * t] = excl;
    cnt[2 * t + 1] = excl + c0;
    __syncthreads();

    // pass B: place transformed entries into stage via LDS cursors
    for (int i = t; i < n; i += 256) {
        ull en = __builtin_nontemporal_load(&src[i]);
        uint w0 = (uint)en;
        int local; uint off4;
        if (isU) { local = (int)(w0 >> 16); off4 = (w0 & 0xFFFF) * (TMPW * 2); }
        else     { local = (int)(w0 >> 17); off4 = (w0 & 0x1FFFF) * (TMPW * 2); }
        int p = atomicAdd(&cnt[local], 1);
        stage[p] = (en & 0xFFFFFFFF00000000ull) | off4;
    }
    __syncthreads();

    // writeout: fully sequential, coalesced, NT
    ull* dst = isU ? (eU + rowPtrU[k * NU + baseN])
                   : (eV + rowPtrV[k * NV + baseN]);
    for (int i = t; i < n; i += 256)
        __builtin_nontemporal_store(stage[i], &dst[i]);
}

// ---------------------------------------------------------------------------
// Merged-support CSR aggregation helper: ONE wave per node, supports
// [K0,K0+NK) in one interleaved latency chain. NT edge loads (stream-once).
template<int K0, int NK, int B, int NNODE>
__device__ __forceinline__ void agg_do(
    const int* __restrict__ rowPtr, const ull* __restrict__ eArr,
    const char* __restrict__ tSrc, int n, uint lane4,
    float* __restrict__ a0, float* __restrict__ a1)
{
    int s[NK], d[NK];
    #pragma unroll
    for (int kk = 0; kk < NK; ++kk) {
        int g = (K0 + kk) * NNODE + n;
        int ss = rowPtr[g];
        int ee = rowPtr[g + 1];     // sentinel covers the last segment
        s[kk] = ss; d[kk] = ee - ss;
    }
    uint ex[NK][B], ev[NK][B], gw[NK][B];
    #pragma unroll
    for (int kk = 0; kk < NK; ++kk)
        #pragma unroll
        for (int i = 0; i < B; ++i) {
            int idx = (i < d[kk]) ? i : 0;
            ull t = __builtin_nontemporal_load(&eArr[s[kk] + idx]);
            ex[kk][i] = (i < d[kk]) ? (uint)t : 0u;
            ev[kk][i] = (uint)(t >> 32);
        }
    #pragma unroll
    for (int kk = 0; kk < NK; ++kk)
        #pragma unroll
        for (int i = 0; i < B; ++i)
            gw[kk][i] = *(const uint*)(tSrc + (ex[kk][i] + lane4 + ((uint)(K0 + kk) << 8)));
    #pragma unroll
    for (int kk = 0; kk < NK; ++kk) {
        float x0 = 0.f, x1 = 0.f;
        #pragma unroll
        for (int i = 0; i < B; ++i)
            if (i < d[kk]) {
                float v = __uint_as_float(ev[kk][i]);
                x0 = fmaf(v, lof(gw[kk][i]), x0);
                x1 = fmaf(v, hif(gw[kk][i]), x1);
            }
        a0[K0 + kk] = x0; a1[K0 + kk] = x1;
    }
    #pragma unroll
    for (int kk = 0; kk < NK; ++kk) {
        if (d[kk] > B) {            // wave-uniform branch
            uint fx[B], fv[B], g1[B];
            #pragma unroll
            for (int i = 0; i < B; ++i) {
                int idx = (B + i < d[kk]) ? B + i : B;
                ull t = __builtin_nontemporal_load(&eArr[s[kk] + idx]);
                fx[i] = (B + i < d[kk]) ? (uint)t : 0u;
                fv[i] = (uint)(t >> 32);
            }
            #pragma unroll
            for (int i = 0; i < B; ++i)
                g1[i] = *(const uint*)(tSrc + (fx[i] + lane4 + ((uint)(K0 + kk) << 8)));
            #pragma unroll
            for (int i = 0; i < B; ++i)
                if (B + i < d[kk]) {
                    float v = __uint_as_float(fv[i]);
                    a0[K0 + kk] = fmaf(v, lof(g1[i]), a0[K0 + kk]);
                    a1[K0 + kk] = fmaf(v, hif(g1[i]), a1[K0 + kk]);
                }
            for (int p = 2 * B; p < d[kk]; ++p) {
                ull t = __builtin_nontemporal_load(&eArr[s[kk] + p]);
                uint g = *(const uint*)(tSrc + ((uint)t + lane4 + ((uint)(K0 + kk) << 8)));
                float v = __uint_as_float((uint)(t >> 32));
                a0[K0 + kk] = fmaf(v, lof(g), a0[K0 + kk]);
                a1[K0 + kk] = fmaf(v, hif(g), a1[K0 + kk]);
            }
        }
    }
}

__device__ __forceinline__ void agg_store(ushort* Xrow, int lane,
                                          const float* a0, const float* a1) {
    #pragma unroll
    for (int k = 0; k < KSUP; ++k) {
        uint payload = (uint)f2bf(fmaxf(a0[k], 0.f)) |
                       ((uint)f2bf(fmaxf(a1[k], 0.f)) << 16);
        if (lane < 50)
            __builtin_nontemporal_store(payload, (uint*)(Xrow + k * FSUP) + lane);
    }
    if (lane < 6)
        __builtin_nontemporal_store(0u, (uint*)(Xrow + 564) + lane);
}

// U-direction: gathers tmpV (64 MB, L3-resident during this kernel)
__global__ __launch_bounds__(256) void agg_u_k(
    const int* __restrict__ rowPtrU, const ull* __restrict__ eU,
    const ushort* __restrict__ tmpV, ushort* __restrict__ Xu)
{
    const int lane = threadIdx.x & 63;
    const int n = blockIdx.x * 4 + (threadIdx.x >> 6);
    const uint lane4 = (uint)(((lane < 50) ? lane : 49) << 2);
    float a0[KSUP], a1[KSUP];
    agg_do<0, KSUP, 4, NU>(rowPtrU, eU, (const char*)tmpV, n, lane4, a0, a1);
    agg_store(Xu + (size_t)n * XW, lane, a0, a1);
}

// V-direction: gathers tmpU (128 MB, L3-resident during this kernel)
__global__ __launch_bounds__(256) void agg_v_k(
    const int* __restrict__ rowPtrV, const ull* __restrict__ eV,
    const ushort* __restrict__ tmpU, ushort* __restrict__ Xv)
{
    const int lane = threadIdx.x & 63;
    const int n = blockIdx.x * 4 + (threadIdx.x >> 6);
    const uint lane4 = (uint)(((lane < 50) ? lane : 49) << 2);
    float a0[KSUP], a1[KSUP];
    agg_do<0, 3, 8, NV>(rowPtrV, eV, (const char*)tmpU, n, lane4, a0, a1);
    agg_do<3, 2, 8, NV>(rowPtrV, eV, (const char*)tmpU, n, lane4, a0, a1);
    agg_store(Xv + (size_t)n * XW, lane, a0, a1);
}

// ---------------------------------------------------------------------------
// final decoder: int2 gathers; basis[b] = dot(embU[u], Vb[v][b]); out=basis@cls
__global__ __launch_bounds__(256) void dec_k(
    const int* __restrict__ ue, const int* __restrict__ ie,
    const ushort* __restrict__ embU, const ushort* __restrict__ Vb,
    const float* __restrict__ cls, float* __restrict__ out, int nE)
{
    int e = blockIdx.x * 8 + (threadIdx.x >> 5);
    if (e >= nE) return;
    int lane = threadIdx.x & 31;
    int u = ue[e], v = ie[e];
    const int2* pu2 = (const int2*)(embU + (size_t)u * DENC);        // 32 int2
    const int2* pv2 = (const int2*)(Vb + (size_t)v * (NBAS * DENC)); // 96 int2
    int2 uu = pu2[lane];                 // cols 4l..4l+3
    int2 bb[NBAS];
    #pragma unroll
    for (int b = 0; b < NBAS; ++b) bb[b] = pv2[b * 32 + lane];
    float uxl = lof((uint)uu.x), uxh = hif((uint)uu.x);
    float uyl = lof((uint)uu.y), uyh = hif((uint)uu.y);
    float s[NBAS];
    #pragma unroll
    for (int b = 0; b < NBAS; ++b) {
        float t = lof((uint)bb[b].x) * uxl;
        t = fmaf(hif((uint)bb[b].x), uxh, t);
        t = fmaf(lof((uint)bb[b].y), uyl, t);
        s[b] = fmaf(hif((uint)bb[b].y), uyh, t);
    }
    #pragma unroll
    for (int off = 16; off; off >>= 1)
        #pragma unroll
        for (int b = 0; b < NBAS; ++b) s[b] += __shfl_xor(s[b], off, 32);
    if (lane < NCLS) {
        float o = 0.f;
        #pragma unroll
        for (int b = 0; b < NBAS; ++b) o += s[b] * cls[b * NCLS + lane];
        out[(size_t)e * NCLS + lane] = o;
    }
}

// ---------------------------------------------------------------------------
extern "C" void kernel_launch(void* const* d_in, const int* in_sizes, int n_in,
                              void* d_out, int out_size, void* d_ws, size_t ws_size,
                              hipStream_t stream) {
    const int*   sup_u  = (const int*)  d_in[0];
    const int*   sup_i  = (const int*)  d_in[1];
    const float* sup_v  = (const float*)d_in[2];
    const float* u_in   = (const float*)d_in[3];
    const float* v_in   = (const float*)d_in[4];
    const float* u_side = (const float*)d_in[5];
    const float* v_side = (const float*)d_in[6];
    const int*   ue     = (const int*)  d_in[7];
    const int*   ie     = (const int*)  d_in[8];
    const float* W_enc  = (const float*)d_in[9];
    const float* Wu1    = (const float*)d_in[10];
    const float* bu1    = (const float*)d_in[11];
    const float* Wi1    = (const float*)d_in[12];
    const float* bi1    = (const float*)d_in[13];
    const float* Wu2    = (const float*)d_in[14];
    const float* Wi2    = (const float*)d_in[15];
    const float* dec_W  = (const float*)d_in[16];
    const float* deccls = (const float*)d_in[17];

    char* ws = (char*)d_ws;
    ushort* u_bf   = (ushort*)(ws);
    ushort* v_bf   = (ushort*)(ws + 102400000LL);
    ushort* Xu     = (ushort*)(ws);
    ushort* Xv     = (ushort*)(ws + 115200000LL);
    // CSR @176M (dead after agg); rowPtr regions padded for the +1 sentinel.
    int*    histU  = (int*)(ws + 176000000LL);          // [5][NU] 2M
    int*    histV  = (int*)(ws + 178000000LL);          // [5][NV] 1M
    int*    rowPtrU= (int*)(ws + 179000000LL);          // 2M + 4 sentinel
    int*    rowPtrV= (int*)(ws + 181200000LL);          // 1M + 4 sentinel
    int*    bsums  = (int*)(ws + 185800000LL);          // 4KB
    int*    bCnt   = (int*)(ws + 185810000LL);          // [1470] contiguous
    ull*    eU     = (ull*)(ws + 186000000LL);          // [2M] 16M
    ull*    eV     = (ull*)(ws + 202000000LL);          // [2M] 16M ends 218M
    // tmp @220M (dead after agg): tmpU [NU][640] 128M, tmpV [NV][640] 64M
    ushort* tmpU   = (ushort*)(ws + 220000000LL);
    ushort* tmpV   = (ushort*)(ws + 348000000LL);       // ends 412M
    // L1 buckets: overlay on tmp region (dead before encoder GEMMs write tmp)
    ull*    bktU   = (ull*)(ws + 220000000LL);          // 980*2560*8  = 20.1M
    ull*    bktV   = (ull*)(ws + 241000000LL);          // 490*5120*8  = 20.1M
    // post-agg overlays:
    ushort* embUbf = (ushort*)(ws + 176000000LL);       // [NU][128] 25.6M (over CSR)
    ushort* embVbf = (ushort*)(ws + 202000000LL);       // [NV][128] 12.8M (over eV)
    ushort* Vb     = (ushort*)(ws + 220000000LL);       // [NV][384] 38.4M (over tmp)
    // weights @412M:
    ushort* WencT2 = (ushort*)(ws + 412000000LL);       // [640][512] 0.66M
    ushort* W2ufT  = (ushort*)(ws + 413000000LL);       // [128][576] 0.15M
    ushort* W2ifT  = (ushort*)(ws + 413200000LL);       // [128][576] 0.15M
    ushort* decbf  = (ushort*)(ws + 413400000LL);       // [384][128] 0.10M

    dim3 blk(256);
    const int gu128 = (NU + 127) / 128;   // 782
    const int gv128 = (NV + 127) / 128;   // 391
    const int gu64  = (NU + 63) / 64;     // 1563
    const int gv64  = (NV + 63) / 64;     // 782
    const int gB    = (NEDGE + CHUNK - 1) / CHUNK;   // 245

    // ---- phase 1: bf16 conversions + CSR build (two-level scatter) ----
    cvt_in_k<<<dim3((NU + NV) * 512 / 4 / 256), blk, 0, stream>>>(u_in, v_in, u_bf, v_bf);
    cvt_wencT2_k<<<dim3(TMPW * 512 / 256), blk, 0, stream>>>(W_enc, WencT2);
    cvt_w2fT2_k<<<dim3((DENC * XW + 255) / 256, 2), blk, 0, stream>>>(Wu2, Wi2, W2ufT, W2ifT);
    cvt_k<<<dim3((NBAS * DENC * DENC / 4 + 255) / 256), blk, 0, stream>>>(
        dec_W, decbf, (long)NBAS * DENC * DENC);

    hipMemsetAsync(histU, 0, 3000000LL, stream);        // histU + histV
    hipMemsetAsync(bCnt, 0, 8192, stream);              // bucket counters
    binhist_k<<<dim3(gB), blk, 0, stream>>>(sup_u, sup_i, sup_v,
                                            histU, histV, bCnt, bktU, bktV);
    scan_reduce_k<<<dim3(245), blk, 0, stream>>>(histU, bsums, KSUP * NU);
    scan_bs_k<<<dim3(1), blk, 0, stream>>>(bsums, 245);
    scan_write_k<<<dim3(245), blk, 0, stream>>>(histU, bsums, rowPtrU, KSUP * NU);
    scan_reduce_k<<<dim3(123), blk, 0, stream>>>(histV, bsums, KSUP * NV);
    scan_bs_k<<<dim3(1), blk, 0, stream>>>(bsums, 123);
    scan_write_k<<<dim3(123), blk, 0, stream>>>(histV, bsums, rowPtrV, KSUP * NV);
    scat3_k<<<dim3(NBT), blk, 0, stream>>>(bCnt, bktU, bktV, rowPtrU, rowPtrV, eU, eV);

    // ---- phase 2: encoder GEMMs (col tile = x fastest -> A panel L3-reuse) ----
    gemm_bf16_k<1><<<dim3(TMPW / 128, gu128), blk, 0, stream>>>(
        u_bf, WencT2, tmpU, NU, TMPW, 512, TMPW);
    gemm_bf16_k<1><<<dim3(TMPW / 128, gv128), blk, 0, stream>>>(
        v_bf, WencT2, tmpV, NV, TMPW, 512, TMPW);

    // ---- phase 3: CSR aggregation, U then V (each gather table L3-fits) ----
    agg_u_k<<<dim3(NU / 4), blk, 0, stream>>>(rowPtrU, eU, tmpV, Xu);
    agg_v_k<<<dim3(NV / 4), blk, 0, stream>>>(rowPtrV, eV, tmpU, Xv);

    // ---- phase 4: side dense -> X cols 500..563 (bf16) ----
    gemm_side_k<<<dim3(gu64), blk, 0, stream>>>(u_side, Wu1, bu1, Xu, NU, DSIDE);
    gemm_side_k<<<dim3(gv64), blk, 0, stream>>>(v_side, Wi1, bi1, Xv, NV, DSIDE);

    // ---- phase 5: dense2 = X @ W2fT (K=576) -> emb bf16 ----
    gemm_bf16_k<1><<<dim3(1, gu128), blk, 0, stream>>>(Xu, W2ufT, embUbf, NU, 128, XW, 128);
    gemm_bf16_k<1><<<dim3(1, gv128), blk, 0, stream>>>(Xv, W2ifT, embVbf, NV, 128, XW, 128);

    // ---- phase 6: decoder precompute on V side: Vb = embV @ decbf^T ----
    gemm_bf16_k<1><<<dim3(3, gv128), blk, 0, stream>>>(embVbf, decbf, Vb, NV, 384, 128, 384);

    // ---- phase 7: final decoder over edges ----
    dec_k<<<dim3(NE / 8), blk, 0, stream>>>(ue, ie, embUbf, Vb, deccls, (float*)d_out, NE);
}

// Round 15
// 926.105 us; speedup vs baseline: 1.3877x; 1.1668x over previous
//
#include <hip/hip_runtime.h>

// Problem constants (fixed by the reference)
#define NU 100000
#define NV 50000
#define KSUP 5
#define ESUP 400000
#define NEDGE (KSUP * ESUP)   // 2,000,000
#define NE 500000
#define DIN 512
#define DGCN 500
#define FSUP 100     // DGCN / KSUP
#define DSIDE 128
#define HSIDE 64
#define DENC 128
#define NBAS 3
#define NCLS 5

#define TMPW 640     // padded tmp width: 5 supports x 128 (256B-aligned slices)
#define XW 576       // X width: 500 gcn + 64 side + 12 pad (K = 9*64)

// two-level scatter geometry (node-range = 512 so V-bucket stages in LDS)
#define BNODE 512
#define RU 196       // ceil(NU/512)
#define RV 98        // ceil(NV/512)
#define NBU (KSUP * RU)   // 980 U buckets
#define NBV (KSUP * RV)   // 490 V buckets
#define NBT (NBU + NBV)   // 1470
#define CAPU 2560    // mean 2048, +11 sigma
#define CAPV 5120    // mean 4096, +16 sigma
#define CHUNK 8192   // edges per block in binhist

__device__ __forceinline__ ushort f2bf(float x) {
    union { float f; unsigned u; } c; c.f = x;
    unsigned r = (c.u + 0x7FFFu + ((c.u >> 16) & 1u)) >> 16;   // RNE
    return (ushort)r;
}
__device__ __forceinline__ float bf2f(ushort h) {
    union { unsigned u; float f; } c; c.u = ((unsigned)h) << 16;
    return c.f;
}
// unpack a u32 holding two bf16 (lo = even col, hi = odd col)
__device__ __forceinline__ float lof(uint g) { return __uint_as_float(g << 16); }
__device__ __forceinline__ float hif(uint g) { return __uint_as_float(g & 0xffff0000u); }

typedef __attribute__((ext_vector_type(4))) float f32x4;
typedef __attribute__((ext_vector_type(8))) short bf16x8;
typedef __attribute__((address_space(3))) void lds_void;
typedef const __attribute__((address_space(1))) void glob_void;
typedef unsigned long long ull;

// ---------------------------------------------------------------------------
// bf16 MFMA GEMM: C[M,N] = A[M,K](bf16,K-major) @ BT[N,K](bf16,K-major)^T
// 128x128 tile, BK=64, 4 waves (2x2). LDS XOR-swizzled via pre-swizzled
// global source (rule #21). Grid: x = col tile (fastest -> A panel L3-reuse),
// y = row tile.
template<int STORE_BF16>
__global__ __launch_bounds__(256) void gemm_bf16_k(
    const ushort* __restrict__ A, const ushort* __restrict__ BT,
    void* __restrict__ Cout, int M, int N, int K, int ldc)
{
    __shared__ ushort As[128 * 64];
    __shared__ ushort Bs[128 * 64];
    const int t = threadIdx.x;
    const int lane = t & 63;
    const int w = t >> 6;
    const int wr = w >> 1, wc = w & 1;
    const int rowBase = blockIdx.y * 128;
    const int colBase = blockIdx.x * 128;

    f32x4 acc[4][4] = {};

    for (int k0 = 0; k0 < K; k0 += 64) {
        #pragma unroll
        for (int i = 0; i < 4; ++i) {
            int chi = i * 256 + t;
            int r = chi >> 3;
            int c = (((chi >> 3) & 7) ^ (chi & 7)) * 8;
            int ga = rowBase + r; if (ga > M - 1) ga = M - 1;
            __builtin_amdgcn_global_load_lds(
                (glob_void*)(A + (size_t)ga * K + k0 + c),
                (lds_void*)(As + (size_t)chi * 8), 16, 0, 0);
            int gb = colBase + r; if (gb > N - 1) gb = N - 1;
            __builtin_amdgcn_global_load_lds(
                (glob_void*)(BT + (size_t)gb * K + k0 + c),
                (lds_void*)(Bs + (size_t)chi * 8), 16, 0, 0);
        }
        __syncthreads();

        #pragma unroll
        for (int kk = 0; kk < 2; ++kk) {
            bf16x8 af[4], bfr[4];
            const int cb2 = (kk * 32 + (lane >> 4) * 8) * 2;
            #pragma unroll
            for (int mi = 0; mi < 4; ++mi) {
                int r = wr * 64 + mi * 16 + (lane & 15);
                int off = (r * 128 + cb2) ^ ((r & 7) << 4);
                af[mi] = *(const bf16x8*)((const char*)As + off);
            }
            #pragma unroll
            for (int nj = 0; nj < 4; ++nj) {
                int r = wc * 64 + nj * 16 + (lane & 15);
                int off = (r * 128 + cb2) ^ ((r & 7) << 4);
                bfr[nj] = *(const bf16x8*)((const char*)Bs + off);
            }
            #pragma unroll
            for (int mi = 0; mi < 4; ++mi)
                #pragma unroll
                for (int nj = 0; nj < 4; ++nj)
                    acc[mi][nj] = __builtin_amdgcn_mfma_f32_16x16x32_bf16(
                        af[mi], bfr[nj], acc[mi][nj], 0, 0, 0);
        }
        __syncthreads();
    }

    #pragma unroll
    for (int mi = 0; mi < 4; ++mi) {
        #pragma unroll
        for (int q = 0; q < 4; ++q) {
            int gr = rowBase + wr * 64 + mi * 16 + (lane >> 4) * 4 + q;
            if (gr >= M) continue;
            #pragma unroll
            for (int nj = 0; nj < 4; ++nj) {
                int gc = colBase + wc * 64 + nj * 16 + (lane & 15);
                float v = acc[mi][nj][q];
                if (STORE_BF16)
                    ((ushort*)Cout)[(size_t)gr * ldc + gc] = f2bf(v);
                else
                    ((float*)Cout)[(size_t)gr * ldc + gc] = v;
            }
        }
    }
}

// ---------------------------------------------------------------------------
// side dense (fp32 compute): writes bf16 relu(A@B+bias) into X cols [500,564)
#define BM 64
#define BN 64
#define BK 16
__global__ __launch_bounds__(256) void gemm_side_k(
    const float* __restrict__ A, const float* __restrict__ B,
    const float* __restrict__ bias, ushort* __restrict__ X,
    int M, int K)
{
    __shared__ float As[BK][BM + 4];
    __shared__ float Bs[BK][BN + 4];
    const int t = threadIdx.x;
    const int rowBase = blockIdx.x * BM;
    const int ty = t >> 4, tx = t & 15;
    float acc[4][4] = {};

    for (int k0 = 0; k0 < K; k0 += BK) {
        #pragma unroll
        for (int p = 0; p < 4; ++p) {
            int r = p * 16 + (t >> 4), kk = t & 15;
            int gr = rowBase + r, gk = k0 + kk;
            As[kk][r] = (gr < M && gk < K) ? A[(size_t)gr * K + gk] : 0.f;
        }
        #pragma unroll
        for (int p = 0; p < 4; ++p) {
            int kk = p * 4 + (t >> 6), j = t & 63;
            int gk = k0 + kk;
            Bs[kk][j] = (j < HSIDE && gk < K) ? B[(size_t)gk * HSIDE + j] : 0.f;
        }
        __syncthreads();
        #pragma unroll
        for (int kk = 0; kk < BK; ++kk) {
            float4 a4 = *reinterpret_cast<const float4*>(&As[kk][ty * 4]);
            float4 b4 = *reinterpret_cast<const float4*>(&Bs[kk][tx * 4]);
            float aa[4] = {a4.x, a4.y, a4.z, a4.w};
            float bb[4] = {b4.x, b4.y, b4.z, b4.w};
            #pragma unroll
            for (int i = 0; i < 4; ++i)
                #pragma unroll
                for (int j = 0; j < 4; ++j)
                    acc[i][j] = fmaf(aa[i], bb[j], acc[i][j]);
        }
        __syncthreads();
    }
    #pragma unroll
    for (int i = 0; i < 4; ++i) {
        int gr = rowBase + ty * 4 + i;
        if (gr >= M) continue;
        #pragma unroll
        for (int j = 0; j < 4; ++j) {
            int gc = tx * 4 + j;
            if (gc < HSIDE)
                X[(size_t)gr * XW + 500 + gc] = f2bf(fmaxf(acc[i][j] + bias[gc], 0.f));
        }
    }
}

// ---------------------------------------------------------------------------
// conversions
__global__ __launch_bounds__(256) void cvt_k(const float* __restrict__ in,
                                             ushort* __restrict__ out, long n) {
    long i = ((long)blockIdx.x * 256 + threadIdx.x) * 4;
    if (i >= n) return;
    float4 v = *(const float4*)(in + i);
    ushort4 o;
    o.x = f2bf(v.x); o.y = f2bf(v.y); o.z = f2bf(v.z); o.w = f2bf(v.w);
    *(ushort4*)(out + i) = o;
}

// fused u/v input conversion
__global__ __launch_bounds__(256) void cvt_in_k(
    const float* __restrict__ u_in, const float* __restrict__ v_in,
    ushort* __restrict__ u_bf, ushort* __restrict__ v_bf)
{
    long i = ((long)blockIdx.x * 256 + threadIdx.x) * 4;
    const long nu = (long)NU * 512;
    const float* src; ushort* dst;
    if (i < nu) { src = u_in; dst = u_bf; }
    else {
        i -= nu;
        if (i >= (long)NV * 512) return;
        src = v_in; dst = v_bf;
    }
    float4 v = *(const float4*)(src + i);
    ushort4 o;
    o.x = f2bf(v.x); o.y = f2bf(v.y); o.z = f2bf(v.z); o.w = f2bf(v.w);
    *(ushort4*)(dst + i) = o;
}

// WencT2[n'][d], n' in [0,640): k=n'>>7, f=n'&127; val = f<100 ? W_enc[k][d][f] : 0
__global__ __launch_bounds__(256) void cvt_wencT2_k(const float* __restrict__ W,
                                                    ushort* __restrict__ out) {
    int idx = blockIdx.x * 256 + threadIdx.x;   // 640*512
    int np = idx >> 9, d = idx & 511;
    int k = np >> 7, f = np & 127;
    float v = (f < FSUP) ? W[((size_t)k * DIN + d) * FSUP + f] : 0.f;
    out[idx] = f2bf(v);
}

// W2fT[j][c] = bf16(W2[c][j]) for c<564, 0 for pad; both U and I via blockIdx.y
__global__ __launch_bounds__(256) void cvt_w2fT2_k(
    const float* __restrict__ Wu2, const float* __restrict__ Wi2,
    ushort* __restrict__ outU, ushort* __restrict__ outI)
{
    int idx = blockIdx.x * 256 + threadIdx.x;   // 128*576
    if (idx >= DENC * XW) return;
    const float* W = blockIdx.y ? Wi2 : Wu2;
    ushort* out = blockIdx.y ? outI : outU;
    int j = idx / XW, c = idx - j * XW;
    float v = (c < DGCN + HSIDE) ? W[(size_t)c * DENC + j] : 0.f;
    out[idx] = f2bf(v);
}

// ---------------------------------------------------------------------------
// Level-1 binning (LDS-only atomics; no global histograms):
// per-block LDS histogram -> ONE global atomicAdd per (block, bucket) to
// reserve a range -> LDS-cursor appends.
// Entry (8B): U: w0=(r_local<<16)|c; V: w0=(c_local<<17)|r; w1=val bits.
__global__ __launch_bounds__(256) void binhist_k(
    const int* __restrict__ su, const int* __restrict__ si,
    const float* __restrict__ sv,
    int* __restrict__ bCnt,              // [NBT] contiguous (U then V)
    ull* __restrict__ bktU, ull* __restrict__ bktV)
{
    __shared__ int lcnt[NBT];
    __shared__ int lbase[NBT];
    const int t = threadIdx.x;
    const int e0 = blockIdx.x * CHUNK;

    for (int i = t; i < NBT; i += 256) lcnt[i] = 0;
    __syncthreads();

    // pass A: LDS bucket histogram
    for (int i = t; i < CHUNK; i += 256) {
        int e = e0 + i;
        if (e >= NEDGE) break;
        int k = e / ESUP;
        int r = su[e], c = si[e];
        atomicAdd(&lcnt[k * RU + (r >> 9)], 1);
        atomicAdd(&lcnt[NBU + k * RV + (c >> 9)], 1);
    }
    __syncthreads();

    // reserve global ranges: one atomic per (block, bucket)
    for (int i = t; i < NBT; i += 256) {
        int n = lcnt[i];
        lbase[i] = n ? atomicAdd(&bCnt[i], n) : 0;
    }
    __syncthreads();
    for (int i = t; i < NBT; i += 256) lcnt[i] = 0;
    __syncthreads();

    // pass B: append via LDS cursors (plain stores -> short sequential runs)
    for (int i = t; i < CHUNK; i += 256) {
        int e = e0 + i;
        if (e >= NEDGE) break;
        int k = e / ESUP;
        int r = su[e], c = si[e];
        ull vb = (ull)(unsigned)__float_as_int(sv[e]) << 32;
        int bu = k * RU + (r >> 9);
        int pu = lbase[bu] + atomicAdd(&lcnt[bu], 1);
        if (pu < CAPU)
            bktU[(size_t)bu * CAPU + pu] = vb | (uint)(((r & 511) << 16) | c);
        int bv = NBU + k * RV + (c >> 9);
        int pv = lbase[bv] + atomicAdd(&lcnt[bv], 1);
        if (pv < CAPV)
            bktV[(size_t)(bv - NBU) * CAPV + pv] = vb | (uint)(((c & 511) << 17) | r);
    }
}

// Exclusive scan of bCnt[NBT] -> bBase. U buckets (0..NBU) sum to NEDGE, so
// V bucket edge-array base = bBase[b] - NEDGE. Also writes rowPtr sentinels.
__global__ __launch_bounds__(256) void bscan_k(const int* __restrict__ bCnt,
                                               int* __restrict__ bBase,
                                               int* __restrict__ rowPtrU,
                                               int* __restrict__ rowPtrV) {
    __shared__ int sm[256];
    const int t = threadIdx.x;
    const int PER = (NBT + 255) / 256;   // 6
    int loc[6]; int s = 0;
    #pragma unroll
    for (int i = 0; i < PER; ++i) {
        int idx = t * PER + i;
        loc[i] = (idx < NBT) ? bCnt[idx] : 0;
        s += loc[i];
    }
    sm[t] = s; __syncthreads();
    int sv = s;
    for (int off = 1; off < 256; off <<= 1) {
        int add = (t >= off) ? sm[t - off] : 0;
        __syncthreads();
        sm[t] += add;
        __syncthreads();
    }
    int base = sm[t] - sv;
    int run = 0;
    #pragma unroll
    for (int i = 0; i < PER; ++i) {
        int idx = t * PER + i;
        if (idx < NBT) bBase[idx] = base + run;
        run += loc[i];
    }
    if (t == 0) {
        rowPtrU[KSUP * NU] = NEDGE;
        rowPtrV[KSUP * NV] = NEDGE;
    }
}

// ---------------------------------------------------------------------------
// Level-2: in-bucket LDS COUNTING SORT -> fully sequential CSR writes AND
// rowPtr derivation (bucket base + in-bucket exclusive offset == rowPtr).
__global__ __launch_bounds__(256) void scat3_k(
    const int* __restrict__ bCnt, const int* __restrict__ bBase,
    const ull* __restrict__ bktU, const ull* __restrict__ bktV,
    int* __restrict__ rowPtrU, int* __restrict__ rowPtrV,
    ull* __restrict__ eU, ull* __restrict__ eV)
{
    __shared__ ull stage[CAPV];          // 40 KB
    __shared__ int cnt[BNODE];           // cursors
    __shared__ int rowOff[BNODE];        // exclusive offsets (kept for rowPtr)
    __shared__ int part[256];
    const int t = threadIdx.x;
    const int b = blockIdx.x;
    const int isU = (b < NBU);
    const ull* src;
    int n, k, baseN, base, NN;
    int* rp;
    if (isU) {
        k = b / RU; baseN = (b % RU) << 9;
        src = bktU + (size_t)b * CAPU;
        n = bCnt[b]; if (n > CAPU) n = CAPU;
        base = bBase[b]; NN = NU; rp = rowPtrU;
    } else {
        int bb = b - NBU;
        k = bb / RV; baseN = (bb % RV) << 9;
        src = bktV + (size_t)bb * CAPV;
        n = bCnt[b]; if (n > CAPV) n = CAPV;
        base = bBase[b] - NEDGE; NN = NV; rp = rowPtrV;
    }

    for (int i = t; i < BNODE; i += 256) cnt[i] = 0;
    __syncthreads();

    // pass A: histogram by local node
    for (int i = t; i < n; i += 256) {
        ull en = __builtin_nontemporal_load(&src[i]);
        uint w0 = (uint)en;
        int local = isU ? (int)(w0 >> 16) : (int)(w0 >> 17);
        atomicAdd(&cnt[local], 1);
    }
    __syncthreads();

    // block exclusive scan of 512 counters (thread t owns 2t, 2t+1)
    int c0 = cnt[2 * t], c1 = cnt[2 * t + 1];
    int s = c0 + c1;
    part[t] = s;
    __syncthreads();
    for (int off = 1; off < 256; off <<= 1) {
        int add = (t >= off) ? part[t - off] : 0;
        __syncthreads();
        part[t] += add;
        __syncthreads();
    }
    int excl = part[t] - s;
    cnt[2 * t] = excl;       rowOff[2 * t] = excl;
    cnt[2 * t + 1] = excl + c0; rowOff[2 * t + 1] = excl + c0;
    __syncthreads();

    // rowPtr for this bucket's nodes (covers degree-0 nodes too)
    for (int i = t; i < BNODE; i += 256) {
        int node = baseN + i;
        if (node < NN) rp[k * NN + node] = base + rowOff[i];
    }

    // pass B: place transformed entries into stage via LDS cursors
    for (int i = t; i < n; i += 256) {
        ull en = __builtin_nontemporal_load(&src[i]);
        uint w0 = (uint)en;
        int local; uint off4;
        if (isU) { local = (int)(w0 >> 16); off4 = (w0 & 0xFFFF) * (TMPW * 2); }
        else     { local = (int)(w0 >> 17); off4 = (w0 & 0x1FFFF) * (TMPW * 2); }
        int p = atomicAdd(&cnt[local], 1);
        stage[p] = (en & 0xFFFFFFFF00000000ull) | off4;
    }
    __syncthreads();

    // writeout: fully sequential, coalesced, NT
    ull* dst = (isU ? eU : eV) + base;
    for (int i = t; i < n; i += 256)
        __builtin_nontemporal_store(stage[i], &dst[i]);
}

// ---------------------------------------------------------------------------
// Merged-support CSR aggregation helper: ONE wave per node, supports
// [K0,K0+NK) in one interleaved latency chain. NT edge loads (stream-once).
template<int K0, int NK, int B, int NNODE>
__device__ __forceinline__ void agg_do(
    const int* __restrict__ rowPtr, const ull* __restrict__ eArr,
    const char* __restrict__ tSrc, int n, uint lane4,
    float* __restrict__ a0, float* __restrict__ a1)
{
    int s[NK], d[NK];
    #pragma unroll
    for (int kk = 0; kk < NK; ++kk) {
        int g = (K0 + kk) * NNODE + n;
        int ss = rowPtr[g];
        int ee = rowPtr[g + 1];     // sentinel covers the last segment
        s[kk] = ss; d[kk] = ee - ss;
    }
    uint ex[NK][B], ev[NK][B], gw[NK][B];
    #pragma unroll
    for (int kk = 0; kk < NK; ++kk)
        #pragma unroll
        for (int i = 0; i < B; ++i) {
            int idx = (i < d[kk]) ? i : 0;
            ull t = __builtin_nontemporal_load(&eArr[s[kk] + idx]);
            ex[kk][i] = (i < d[kk]) ? (uint)t : 0u;
            ev[kk][i] = (uint)(t >> 32);
        }
    #pragma unroll
    for (int kk = 0; kk < NK; ++kk)
        #pragma unroll
        for (int i = 0; i < B; ++i)
            gw[kk][i] = *(const uint*)(tSrc + (ex[kk][i] + lane4 + ((uint)(K0 + kk) << 8)));
    #pragma unroll
    for (int kk = 0; kk < NK; ++kk) {
        float x0 = 0.f, x1 = 0.f;
        #pragma unroll
        for (int i = 0; i < B; ++i)
            if (i < d[kk]) {
                float v = __uint_as_float(ev[kk][i]);
                x0 = fmaf(v, lof(gw[kk][i]), x0);
                x1 = fmaf(v, hif(gw[kk][i]), x1);
            }
        a0[K0 + kk] = x0; a1[K0 + kk] = x1;
    }
    #pragma unroll
    for (int kk = 0; kk < NK; ++kk) {
        if (d[kk] > B) {            // wave-uniform branch
            uint fx[B], fv[B], g1[B];
            #pragma unroll
            for (int i = 0; i < B; ++i) {
                int idx = (B + i < d[kk]) ? B + i : B;
                ull t = __builtin_nontemporal_load(&eArr[s[kk] + idx]);
                fx[i] = (B + i < d[kk]) ? (uint)t : 0u;
                fv[i] = (uint)(t >> 32);
            }
            #pragma unroll
            for (int i = 0; i < B; ++i)
                g1[i] = *(const uint*)(tSrc + (fx[i] + lane4 + ((uint)(K0 + kk) << 8)));
            #pragma unroll
            for (int i = 0; i < B; ++i)
                if (B + i < d[kk]) {
                    float v = __uint_as_float(fv[i]);
                    a0[K0 + kk] = fmaf(v, lof(g1[i]), a0[K0 + kk]);
                    a1[K0 + kk] = fmaf(v, hif(g1[i]), a1[K0 + kk]);
                }
            for (int p = 2 * B; p < d[kk]; ++p) {
                ull t = __builtin_nontemporal_load(&eArr[s[kk] + p]);
                uint g = *(const uint*)(tSrc + ((uint)t + lane4 + ((uint)(K0 + kk) << 8)));
                float v = __uint_as_float((uint)(t >> 32));
                a0[K0 + kk] = fmaf(v, lof(g), a0[K0 + kk]);
                a1[K0 + kk] = fmaf(v, hif(g), a1[K0 + kk]);
            }
        }
    }
}

__device__ __forceinline__ void agg_store(ushort* Xrow, int lane,
                                          const float* a0, const float* a1) {
    #pragma unroll
    for (int k = 0; k < KSUP; ++k) {
        uint payload = (uint)f2bf(fmaxf(a0[k], 0.f)) |
                       ((uint)f2bf(fmaxf(a1[k], 0.f)) << 16);
        if (lane < 50)
            __builtin_nontemporal_store(payload, (uint*)(Xrow + k * FSUP) + lane);
    }
    if (lane < 6)
        __builtin_nontemporal_store(0u, (uint*)(Xrow + 564) + lane);
}

// U-direction: gathers tmpV (64 MB, L3-resident during this kernel)
__global__ __launch_bounds__(256) void agg_u_k(
    const int* __restrict__ rowPtrU, const ull* __restrict__ eU,
    const ushort* __restrict__ tmpV, ushort* __restrict__ Xu)
{
    const int lane = threadIdx.x & 63;
    const int n = blockIdx.x * 4 + (threadIdx.x >> 6);
    const uint lane4 = (uint)(((lane < 50) ? lane : 49) << 2);
    float a0[KSUP], a1[KSUP];
    agg_do<0, KSUP, 4, NU>(rowPtrU, eU, (const char*)tmpV, n, lane4, a0, a1);
    agg_store(Xu + (size_t)n * XW, lane, a0, a1);
}

// V-direction: gathers tmpU (128 MB, L3-resident during this kernel)
__global__ __launch_bounds__(256) void agg_v_k(
    const int* __restrict__ rowPtrV, const ull* __restrict__ eV,
    const ushort* __restrict__ tmpU, ushort* __restrict__ Xv)
{
    const int lane = threadIdx.x & 63;
    const int n = blockIdx.x * 4 + (threadIdx.x >> 6);
    const uint lane4 = (uint)(((lane < 50) ? lane : 49) << 2);
    float a0[KSUP], a1[KSUP];
    agg_do<0, 3, 8, NV>(rowPtrV, eV, (const char*)tmpU, n, lane4, a0, a1);
    agg_do<3, 2, 8, NV>(rowPtrV, eV, (const char*)tmpU, n, lane4, a0, a1);
    agg_store(Xv + (size_t)n * XW, lane, a0, a1);
}

// ---------------------------------------------------------------------------
// final decoder: int2 gathers; basis[b] = dot(embU[u], Vb[v][b]); out=basis@cls
__global__ __launch_bounds__(256) void dec_k(
    const int* __restrict__ ue, const int* __restrict__ ie,
    const ushort* __restrict__ embU, const ushort* __restrict__ Vb,
    const float* __restrict__ cls, float* __restrict__ out, int nE)
{
    int e = blockIdx.x * 8 + (threadIdx.x >> 5);
    if (e >= nE) return;
    int lane = threadIdx.x & 31;
    int u = ue[e], v = ie[e];
    const int2* pu2 = (const int2*)(embU + (size_t)u * DENC);        // 32 int2
    const int2* pv2 = (const int2*)(Vb + (size_t)v * (NBAS * DENC)); // 96 int2
    int2 uu = pu2[lane];                 // cols 4l..4l+3
    int2 bb[NBAS];
    #pragma unroll
    for (int b = 0; b < NBAS; ++b) bb[b] = pv2[b * 32 + lane];
    float uxl = lof((uint)uu.x), uxh = hif((uint)uu.x);
    float uyl = lof((uint)uu.y), uyh = hif((uint)uu.y);
    float s[NBAS];
    #pragma unroll
    for (int b = 0; b < NBAS; ++b) {
        float t = lof((uint)bb[b].x) * uxl;
        t = fmaf(hif((uint)bb[b].x), uxh, t);
        t = fmaf(lof((uint)bb[b].y), uyl, t);
        s[b] = fmaf(hif((uint)bb[b].y), uyh, t);
    }
    #pragma unroll
    for (int off = 16; off; off >>= 1)
        #pragma unroll
        for (int b = 0; b < NBAS; ++b) s[b] += __shfl_xor(s[b], off, 32);
    if (lane < NCLS) {
        float o = 0.f;
        #pragma unroll
        for (int b = 0; b < NBAS; ++b) o += s[b] * cls[b * NCLS + lane];
        out[(size_t)e * NCLS + lane] = o;
    }
}

// ---------------------------------------------------------------------------
extern "C" void kernel_launch(void* const* d_in, const int* in_sizes, int n_in,
                              void* d_out, int out_size, void* d_ws, size_t ws_size,
                              hipStream_t stream) {
    const int*   sup_u  = (const int*)  d_in[0];
    const int*   sup_i  = (const int*)  d_in[1];
    const float* sup_v  = (const float*)d_in[2];
    const float* u_in   = (const float*)d_in[3];
    const float* v_in   = (const float*)d_in[4];
    const float* u_side = (const float*)d_in[5];
    const float* v_side = (const float*)d_in[6];
    const int*   ue     = (const int*)  d_in[7];
    const int*   ie     = (const int*)  d_in[8];
    const float* W_enc  = (const float*)d_in[9];
    const float* Wu1    = (const float*)d_in[10];
    const float* bu1    = (const float*)d_in[11];
    const float* Wi1    = (const float*)d_in[12];
    const float* bi1    = (const float*)d_in[13];
    const float* Wu2    = (const float*)d_in[14];
    const float* Wi2    = (const float*)d_in[15];
    const float* dec_W  = (const float*)d_in[16];
    const float* deccls = (const float*)d_in[17];

    char* ws = (char*)d_ws;
    ushort* u_bf   = (ushort*)(ws);
    ushort* v_bf   = (ushort*)(ws + 102400000LL);
    ushort* Xu     = (ushort*)(ws);
    ushort* Xv     = (ushort*)(ws + 115200000LL);
    // CSR @176M (dead after agg); rowPtr regions padded for the +1 sentinel.
    int*    rowPtrU= (int*)(ws + 179000000LL);          // 2M + 4 sentinel
    int*    rowPtrV= (int*)(ws + 181200000LL);          // 1M + 4 sentinel
    int*    bBase  = (int*)(ws + 185780000LL);          // [1470]
    int*    bCnt   = (int*)(ws + 185810000LL);          // [1470] contiguous
    ull*    eU     = (ull*)(ws + 186000000LL);          // [2M] 16M
    ull*    eV     = (ull*)(ws + 202000000LL);          // [2M] 16M ends 218M
    // tmp @220M (dead after agg): tmpU [NU][640] 128M, tmpV [NV][640] 64M
    ushort* tmpU   = (ushort*)(ws + 220000000LL);
    ushort* tmpV   = (ushort*)(ws + 348000000LL);       // ends 412M
    // L1 buckets: overlay on tmp region (dead before encoder GEMMs write tmp)
    ull*    bktU   = (ull*)(ws + 220000000LL);          // 980*2560*8  = 20.1M
    ull*    bktV   = (ull*)(ws + 241000000LL);          // 490*5120*8  = 20.1M
    // post-agg overlays:
    ushort* embUbf = (ushort*)(ws + 176000000LL);       // [NU][128] 25.6M (over CSR)
    ushort* embVbf = (ushort*)(ws + 202000000LL);       // [NV][128] 12.8M (over eV)
    ushort* Vb     = (ushort*)(ws + 220000000LL);       // [NV][384] 38.4M (over tmp)
    // weights @412M:
    ushort* WencT2 = (ushort*)(ws + 412000000LL);       // [640][512] 0.66M
    ushort* W2ufT  = (ushort*)(ws + 413000000LL);       // [128][576] 0.15M
    ushort* W2ifT  = (ushort*)(ws + 413200000LL);       // [128][576] 0.15M
    ushort* decbf  = (ushort*)(ws + 413400000LL);       // [384][128] 0.10M

    dim3 blk(256);
    const int gu128 = (NU + 127) / 128;   // 782
    const int gv128 = (NV + 127) / 128;   // 391
    const int gu64  = (NU + 63) / 64;     // 1563
    const int gv64  = (NV + 63) / 64;     // 782
    const int gB    = (NEDGE + CHUNK - 1) / CHUNK;   // 245

    // ---- phase 1: bf16 conversions + CSR build (hist-free two-level sort) ----
    cvt_in_k<<<dim3((NU + NV) * 512 / 4 / 256), blk, 0, stream>>>(u_in, v_in, u_bf, v_bf);
    cvt_wencT2_k<<<dim3(TMPW * 512 / 256), blk, 0, stream>>>(W_enc, WencT2);
    cvt_w2fT2_k<<<dim3((DENC * XW + 255) / 256, 2), blk, 0, stream>>>(Wu2, Wi2, W2ufT, W2ifT);
    cvt_k<<<dim3((NBAS * DENC * DENC / 4 + 255) / 256), blk, 0, stream>>>(
        dec_W, decbf, (long)NBAS * DENC * DENC);

    hipMemsetAsync(bCnt, 0, 8192, stream);              // bucket counters
    binhist_k<<<dim3(gB), blk, 0, stream>>>(sup_u, sup_i, sup_v, bCnt, bktU, bktV);
    bscan_k<<<dim3(1), blk, 0, stream>>>(bCnt, bBase, rowPtrU, rowPtrV);
    scat3_k<<<dim3(NBT), blk, 0, stream>>>(bCnt, bBase, bktU, bktV,
                                           rowPtrU, rowPtrV, eU, eV);

    // ---- phase 2: encoder GEMMs (col tile = x fastest -> A panel L3-reuse) ----
    gemm_bf16_k<1><<<dim3(TMPW / 128, gu128), blk, 0, stream>>>(
        u_bf, WencT2, tmpU, NU, TMPW, 512, TMPW);
    gemm_bf16_k<1><<<dim3(TMPW / 128, gv128), blk, 0, stream>>>(
        v_bf, WencT2, tmpV, NV, TMPW, 512, TMPW);

    // ---- phase 3: CSR aggregation, U then V (each gather table L3-fits) ----
    agg_u_k<<<dim3(NU / 4), blk, 0, stream>>>(rowPtrU, eU, tmpV, Xu);
    agg_v_k<<<dim3(NV / 4), blk, 0, stream>>>(rowPtrV, eV, tmpU, Xv);

    // ---- phase 4: side dense -> X cols 500..563 (bf16) ----
    gemm_side_k<<<dim3(gu64), blk, 0, stream>>>(u_side, Wu1, bu1, Xu, NU, DSIDE);
    gemm_side_k<<<dim3(gv64), blk, 0, stream>>>(v_side, Wi1, bi1, Xv, NV, DSIDE);

    // ---- phase 5: dense2 = X @ W2fT (K=576) -> emb bf16 ----
    gemm_bf16_k<1><<<dim3(1, gu128), blk, 0, stream>>>(Xu, W2ufT, embUbf, NU, 128, XW, 128);
    gemm_bf16_k<1><<<dim3(1, gv128), blk, 0, stream>>>(Xv, W2ifT, embVbf, NV, 128, XW, 128);

    // ---- phase 6: decoder precompute on V side: Vb = embV @ decbf^T ----
    gemm_bf16_k<1><<<dim3(3, gv128), blk, 0, stream>>>(embVbf, decbf, Vb, NV, 384, 128, 384);

    // ---- phase 7: final decoder over edges ----
    dec_k<<<dim3(NE / 8), blk, 0, stream>>>(ue, ie, embUbf, Vb, deccls, (float*)d_out, NE);
}

// Round 16
// 869.911 us; speedup vs baseline: 1.4774x; 1.0646x over previous
//
#include <hip/hip_runtime.h>

// Problem constants (fixed by the reference)
#define NU 100000
#define NV 50000
#define KSUP 5
#define ESUP 400000
#define NEDGE (KSUP * ESUP)   // 2,000,000
#define NE 500000
#define DIN 512
#define DGCN 500
#define FSUP 100     // DGCN / KSUP
#define DSIDE 128
#define HSIDE 64
#define DENC 128
#define NBAS 3
#define NCLS 5

#define TMPW 640     // padded tmp width: 5 supports x 128 (256B-aligned slices)
#define XW 576       // X width: 500 gcn + 64 side + 12 pad (K = 9*64)

// two-level scatter geometry (node-range = 512 so V-bucket stages in LDS)
#define BNODE 512
#define RU 196       // ceil(NU/512)
#define RV 98        // ceil(NV/512)
#define NBU (KSUP * RU)   // 980 U buckets
#define NBV (KSUP * RV)   // 490 V buckets
#define NBT (NBU + NBV)   // 1470
#define CAPU 2560    // mean 2048, +11 sigma
#define CAPV 5120    // mean 4096, +16 sigma
#define CHUNK 8192   // edges per block in binhist

// grid-partition constants
#define GU128 782    // ceil(NU/128)
#define GV128 391    // ceil(NV/128)
#define GU64 1563    // ceil(NU/64)
#define GV64 782     // ceil(NV/64)
#define GBIN 245     // ceil(NEDGE/CHUNK)
#define PB1 (GBIN + 1280)          // + wencT2 blocks (640*512/256)
#define PB2 (PB1 + 288)            // + W2u blocks (128*576/256)
#define PB3 (PB2 + 288)            // + W2i blocks
#define PB4 (PB3 + 48)             // + dec cvt blocks (384*128/4/256)
#define PTOT (PB4 + 75000)         // + cvt_in blocks ((NU+NV)*512/4/256)

__device__ __forceinline__ ushort f2bf(float x) {
    union { float f; unsigned u; } c; c.f = x;
    unsigned r = (c.u + 0x7FFFu + ((c.u >> 16) & 1u)) >> 16;   // RNE
    return (ushort)r;
}
// unpack a u32 holding two bf16 (lo = even col, hi = odd col)
__device__ __forceinline__ float lof(uint g) { return __uint_as_float(g << 16); }
__device__ __forceinline__ float hif(uint g) { return __uint_as_float(g & 0xffff0000u); }

typedef __attribute__((ext_vector_type(4))) float f32x4;
typedef __attribute__((ext_vector_type(8))) short bf16x8;
typedef __attribute__((address_space(3))) void lds_void;
typedef const __attribute__((address_space(1))) void glob_void;
typedef unsigned long long ull;

// ---------------------------------------------------------------------------
// bf16 MFMA GEMM body: C[M,N](bf16) = A[M,K](bf16,K-major) @ BT[N,K]^T
// 128x128 tile, BK=64, 4 waves (2x2). LDS XOR-swizzled via pre-swizzled
// global source (rule #21). ONE call site per kernel (single __shared__).
__device__ __forceinline__ void gemm_body(
    const ushort* __restrict__ A, const ushort* __restrict__ BT,
    ushort* __restrict__ Cout, int M, int N, int K, int ldc,
    int rowBase, int colBase)
{
    __shared__ ushort As[128 * 64];
    __shared__ ushort Bs[128 * 64];
    const int t = threadIdx.x;
    const int lane = t & 63;
    const int w = t >> 6;
    const int wr = w >> 1, wc = w & 1;

    f32x4 acc[4][4] = {};

    for (int k0 = 0; k0 < K; k0 += 64) {
        #pragma unroll
        for (int i = 0; i < 4; ++i) {
            int chi = i * 256 + t;
            int r = chi >> 3;
            int c = (((chi >> 3) & 7) ^ (chi & 7)) * 8;
            int ga = rowBase + r; if (ga > M - 1) ga = M - 1;
            __builtin_amdgcn_global_load_lds(
                (glob_void*)(A + (size_t)ga * K + k0 + c),
                (lds_void*)(As + (size_t)chi * 8), 16, 0, 0);
            int gb = colBase + r; if (gb > N - 1) gb = N - 1;
            __builtin_amdgcn_global_load_lds(
                (glob_void*)(BT + (size_t)gb * K + k0 + c),
                (lds_void*)(Bs + (size_t)chi * 8), 16, 0, 0);
        }
        __syncthreads();

        #pragma unroll
        for (int kk = 0; kk < 2; ++kk) {
            bf16x8 af[4], bfr[4];
            const int cb2 = (kk * 32 + (lane >> 4) * 8) * 2;
            #pragma unroll
            for (int mi = 0; mi < 4; ++mi) {
                int r = wr * 64 + mi * 16 + (lane & 15);
                int off = (r * 128 + cb2) ^ ((r & 7) << 4);
                af[mi] = *(const bf16x8*)((const char*)As + off);
            }
            #pragma unroll
            for (int nj = 0; nj < 4; ++nj) {
                int r = wc * 64 + nj * 16 + (lane & 15);
                int off = (r * 128 + cb2) ^ ((r & 7) << 4);
                bfr[nj] = *(const bf16x8*)((const char*)Bs + off);
            }
            #pragma unroll
            for (int mi = 0; mi < 4; ++mi)
                #pragma unroll
                for (int nj = 0; nj < 4; ++nj)
                    acc[mi][nj] = __builtin_amdgcn_mfma_f32_16x16x32_bf16(
                        af[mi], bfr[nj], acc[mi][nj], 0, 0, 0);
        }
        __syncthreads();
    }

    #pragma unroll
    for (int mi = 0; mi < 4; ++mi) {
        #pragma unroll
        for (int q = 0; q < 4; ++q) {
            int gr = rowBase + wr * 64 + mi * 16 + (lane >> 4) * 4 + q;
            if (gr >= M) continue;
            #pragma unroll
            for (int nj = 0; nj < 4; ++nj) {
                int gc = colBase + wc * 64 + nj * 16 + (lane & 15);
                Cout[(size_t)gr * ldc + gc] = f2bf(acc[mi][nj][q]);
            }
        }
    }
}

// generic single-matrix GEMM (used for Vb precompute)
__global__ __launch_bounds__(256) void gemm_bf16_k(
    const ushort* __restrict__ A, const ushort* __restrict__ BT,
    ushort* __restrict__ Cout, int M, int N, int K, int ldc)
{
    gemm_body(A, BT, Cout, M, N, K, ldc, blockIdx.y * 128, blockIdx.x * 128);
}

// fused encoder GEMM: U rows then V rows via blockIdx.y partition
__global__ __launch_bounds__(256) void gemm_enc_k(
    const ushort* __restrict__ u_bf, const ushort* __restrict__ v_bf,
    const ushort* __restrict__ WencT2,
    ushort* __restrict__ tmpU, ushort* __restrict__ tmpV)
{
    int y = blockIdx.y;
    const ushort* A; ushort* C; int M, rowBase;
    if (y < GU128) { A = u_bf; C = tmpU; M = NU; rowBase = y * 128; }
    else           { A = v_bf; C = tmpV; M = NV; rowBase = (y - GU128) * 128; }
    gemm_body(A, WencT2, C, M, TMPW, 512, TMPW, rowBase, blockIdx.x * 128);
}

// fused dense2 GEMM: emb = X @ W2fT (K=576, N=128)
__global__ __launch_bounds__(256) void gemm_d2_k(
    const ushort* __restrict__ Xu, const ushort* __restrict__ Xv,
    const ushort* __restrict__ W2u, const ushort* __restrict__ W2i,
    ushort* __restrict__ embU, ushort* __restrict__ embV)
{
    int y = blockIdx.y;
    const ushort* A; const ushort* BT; ushort* C; int M, rowBase;
    if (y < GU128) { A = Xu; BT = W2u; C = embU; M = NU; rowBase = y * 128; }
    else           { A = Xv; BT = W2i; C = embV; M = NV; rowBase = (y - GU128) * 128; }
    gemm_body(A, BT, C, M, DENC, XW, DENC, rowBase, 0);
}

// ---------------------------------------------------------------------------
// side dense body (fp32): writes bf16 relu(A@B+bias) into X cols [500,564)
#define BM 64
#define BN 64
#define BK 16
__device__ __forceinline__ void side_body(
    const float* __restrict__ A, const float* __restrict__ B,
    const float* __restrict__ bias, ushort* __restrict__ X,
    int M, int K, int rowBase)
{
    __shared__ float As[BK][BM + 4];
    __shared__ float Bs[BK][BN + 4];
    const int t = threadIdx.x;
    const int ty = t >> 4, tx = t & 15;
    float acc[4][4] = {};

    for (int k0 = 0; k0 < K; k0 += BK) {
        #pragma unroll
        for (int p = 0; p < 4; ++p) {
            int r = p * 16 + (t >> 4), kk = t & 15;
            int gr = rowBase + r, gk = k0 + kk;
            As[kk][r] = (gr < M && gk < K) ? A[(size_t)gr * K + gk] : 0.f;
        }
        #pragma unroll
        for (int p = 0; p < 4; ++p) {
            int kk = p * 4 + (t >> 6), j = t & 63;
            int gk = k0 + kk;
            Bs[kk][j] = (j < HSIDE && gk < K) ? B[(size_t)gk * HSIDE + j] : 0.f;
        }
        __syncthreads();
        #pragma unroll
        for (int kk = 0; kk < BK; ++kk) {
            float4 a4 = *reinterpret_cast<const float4*>(&As[kk][ty * 4]);
            float4 b4 = *reinterpret_cast<const float4*>(&Bs[kk][tx * 4]);
            float aa[4] = {a4.x, a4.y, a4.z, a4.w};
            float bb[4] = {b4.x, b4.y, b4.z, b4.w};
            #pragma unroll
            for (int i = 0; i < 4; ++i)
                #pragma unroll
                for (int j = 0; j < 4; ++j)
                    acc[i][j] = fmaf(aa[i], bb[j], acc[i][j]);
        }
        __syncthreads();
    }
    #pragma unroll
    for (int i = 0; i < 4; ++i) {
        int gr = rowBase + ty * 4 + i;
        if (gr >= M) continue;
        #pragma unroll
        for (int j = 0; j < 4; ++j) {
            int gc = tx * 4 + j;
            if (gc < HSIDE)
                X[(size_t)gr * XW + 500 + gc] = f2bf(fmaxf(acc[i][j] + bias[gc], 0.f));
        }
    }
}

__global__ __launch_bounds__(256) void side_k(
    const float* __restrict__ uS, const float* __restrict__ vS,
    const float* __restrict__ Wu1, const float* __restrict__ bu1,
    const float* __restrict__ Wi1, const float* __restrict__ bi1,
    ushort* __restrict__ Xu, ushort* __restrict__ Xv)
{
    int b = blockIdx.x;
    const float *A, *B, *bias; ushort* X; int M, rowBase;
    if (b < GU64) { A = uS; B = Wu1; bias = bu1; X = Xu; M = NU; rowBase = b * 64; }
    else          { A = vS; B = Wi1; bias = bi1; X = Xv; M = NV; rowBase = (b - GU64) * 64; }
    side_body(A, B, bias, X, M, DSIDE, rowBase);
}

// ---------------------------------------------------------------------------
// prep_k: fused {binhist (first, latency-bound) | weight cvts | input cvt
// (BW-bound)} — independent phases overlap on the CU pool.
__global__ __launch_bounds__(256) void prep_k(
    const int* __restrict__ su, const int* __restrict__ si,
    const float* __restrict__ sv,
    int* __restrict__ bCnt, ull* __restrict__ bktU, ull* __restrict__ bktV,
    const float* __restrict__ W_enc, ushort* __restrict__ WencT2,
    const float* __restrict__ Wu2, const float* __restrict__ Wi2,
    ushort* __restrict__ W2ufT, ushort* __restrict__ W2ifT,
    const float* __restrict__ dec_W, ushort* __restrict__ decbf,
    const float* __restrict__ u_in, const float* __restrict__ v_in,
    ushort* __restrict__ u_bf, ushort* __restrict__ v_bf)
{
    __shared__ int lcnt[NBT];
    __shared__ int lbase[NBT];
    const int bid = blockIdx.x;
    const int t = threadIdx.x;

    if (bid < GBIN) {
        // ---- level-1 binning (LDS-only histogram + range reservation) ----
        const int e0 = bid * CHUNK;
        for (int i = t; i < NBT; i += 256) lcnt[i] = 0;
        __syncthreads();
        for (int i = t; i < CHUNK; i += 256) {
            int e = e0 + i;
            if (e >= NEDGE) break;
            int k = e / ESUP;
            int r = su[e], c = si[e];
            atomicAdd(&lcnt[k * RU + (r >> 9)], 1);
            atomicAdd(&lcnt[NBU + k * RV + (c >> 9)], 1);
        }
        __syncthreads();
        for (int i = t; i < NBT; i += 256) {
            int n = lcnt[i];
            lbase[i] = n ? atomicAdd(&bCnt[i], n) : 0;
        }
        __syncthreads();
        for (int i = t; i < NBT; i += 256) lcnt[i] = 0;
        __syncthreads();
        for (int i = t; i < CHUNK; i += 256) {
            int e = e0 + i;
            if (e >= NEDGE) break;
            int k = e / ESUP;
            int r = su[e], c = si[e];
            ull vb = (ull)(unsigned)__float_as_int(sv[e]) << 32;
            int bu = k * RU + (r >> 9);
            int pu = lbase[bu] + atomicAdd(&lcnt[bu], 1);
            if (pu < CAPU)
                bktU[(size_t)bu * CAPU + pu] = vb | (uint)(((r & 511) << 16) | c);
            int bv = NBU + k * RV + (c >> 9);
            int pv = lbase[bv] + atomicAdd(&lcnt[bv], 1);
            if (pv < CAPV)
                bktV[(size_t)(bv - NBU) * CAPV + pv] = vb | (uint)(((c & 511) << 17) | r);
        }
    } else if (bid < PB1) {
        // ---- WencT2[n'][d]: k=n'>>7, f=n'&127; f<100 ? W_enc[k][d][f] : 0 ----
        int idx = (bid - GBIN) * 256 + t;            // 640*512
        int np = idx >> 9, d = idx & 511;
        int k = np >> 7, f = np & 127;
        float v = (f < FSUP) ? W_enc[((size_t)k * DIN + d) * FSUP + f] : 0.f;
        WencT2[idx] = f2bf(v);
    } else if (bid < PB3) {
        // ---- W2fT[j][c] = W2[c][j] (c<564, pad 0) for U then I ----
        int which = (bid < PB2) ? 0 : 1;
        int idx = (bid - (which ? PB2 : PB1)) * 256 + t;   // 128*576
        const float* W = which ? Wi2 : Wu2;
        ushort* out = which ? W2ifT : W2ufT;
        int j = idx / XW, c = idx - j * XW;
        float v = (c < DGCN + HSIDE) ? W[(size_t)c * DENC + j] : 0.f;
        out[idx] = f2bf(v);
    } else if (bid < PB4) {
        // ---- decbf = bf16(dec_W) flat ----
        long i = ((long)(bid - PB3) * 256 + t) * 4;
        if (i < (long)NBAS * DENC * DENC) {
            float4 v = *(const float4*)(dec_W + i);
            ushort4 o;
            o.x = f2bf(v.x); o.y = f2bf(v.y); o.z = f2bf(v.z); o.w = f2bf(v.w);
            *(ushort4*)(decbf + i) = o;
        }
    } else {
        // ---- input conversion u_in/v_in -> bf16 ----
        long i = ((long)(bid - PB4) * 256 + t) * 4;
        const long nu = (long)NU * 512;
        const float* src; ushort* dst;
        if (i < nu) { src = u_in; dst = u_bf; }
        else {
            i -= nu;
            if (i >= (long)NV * 512) return;
            src = v_in; dst = v_bf;
        }
        float4 v = *(const float4*)(src + i);
        ushort4 o;
        o.x = f2bf(v.x); o.y = f2bf(v.y); o.z = f2bf(v.z); o.w = f2bf(v.w);
        *(ushort4*)(dst + i) = o;
    }
}

// Exclusive scan of bCnt[NBT] -> bBase; writes rowPtr sentinels.
__global__ __launch_bounds__(256) void bscan_k(const int* __restrict__ bCnt,
                                               int* __restrict__ bBase,
                                               int* __restrict__ rowPtrU,
                                               int* __restrict__ rowPtrV) {
    __shared__ int sm[256];
    const int t = threadIdx.x;
    const int PER = (NBT + 255) / 256;   // 6
    int loc[6]; int s = 0;
    #pragma unroll
    for (int i = 0; i < PER; ++i) {
        int idx = t * PER + i;
        loc[i] = (idx < NBT) ? bCnt[idx] : 0;
        s += loc[i];
    }
    sm[t] = s; __syncthreads();
    int sv = s;
    for (int off = 1; off < 256; off <<= 1) {
        int add = (t >= off) ? sm[t - off] : 0;
        __syncthreads();
        sm[t] += add;
        __syncthreads();
    }
    int base = sm[t] - sv;
    int run = 0;
    #pragma unroll
    for (int i = 0; i < PER; ++i) {
        int idx = t * PER + i;
        if (idx < NBT) bBase[idx] = base + run;
        run += loc[i];
    }
    if (t == 0) {
        rowPtrU[KSUP * NU] = NEDGE;
        rowPtrV[KSUP * NV] = NEDGE;
    }
}

// ---------------------------------------------------------------------------
// Level-2: in-bucket LDS counting sort -> fully sequential CSR writes AND
// rowPtr derivation (bucket base + in-bucket exclusive offset == rowPtr).
__global__ __launch_bounds__(256) void scat3_k(
    const int* __restrict__ bCnt, const int* __restrict__ bBase,
    const ull* __restrict__ bktU, const ull* __restrict__ bktV,
    int* __restrict__ rowPtrU, int* __restrict__ rowPtrV,
    ull* __restrict__ eU, ull* __restrict__ eV)
{
    __shared__ ull stage[CAPV];          // 40 KB
    __shared__ int cnt[BNODE];
    __shared__ int rowOff[BNODE];
    __shared__ int part[256];
    const int t = threadIdx.x;
    const int b = blockIdx.x;
    const int isU = (b < NBU);
    const ull* src;
    int n, k, baseN, base, NN;
    int* rp;
    if (isU) {
        k = b / RU; baseN = (b % RU) << 9;
        src = bktU + (size_t)b * CAPU;
        n = bCnt[b]; if (n > CAPU) n = CAPU;
        base = bBase[b]; NN = NU; rp = rowPtrU;
    } else {
        int bb = b - NBU;
        k = bb / RV; baseN = (bb % RV) << 9;
        src = bktV + (size_t)bb * CAPV;
        n = bCnt[b]; if (n > CAPV) n = CAPV;
        base = bBase[b] - NEDGE; NN = NV; rp = rowPtrV;
    }

    for (int i = t; i < BNODE; i += 256) cnt[i] = 0;
    __syncthreads();

    for (int i = t; i < n; i += 256) {
        ull en = __builtin_nontemporal_load(&src[i]);
        uint w0 = (uint)en;
        int local = isU ? (int)(w0 >> 16) : (int)(w0 >> 17);
        atomicAdd(&cnt[local], 1);
    }
    __syncthreads();

    int c0 = cnt[2 * t], c1 = cnt[2 * t + 1];
    int s = c0 + c1;
    part[t] = s;
    __syncthreads();
    for (int off = 1; off < 256; off <<= 1) {
        int add = (t >= off) ? part[t - off] : 0;
        __syncthreads();
        part[t] += add;
        __syncthreads();
    }
    int excl = part[t] - s;
    cnt[2 * t] = excl;          rowOff[2 * t] = excl;
    cnt[2 * t + 1] = excl + c0; rowOff[2 * t + 1] = excl + c0;
    __syncthreads();

    for (int i = t; i < BNODE; i += 256) {
        int node = baseN + i;
        if (node < NN) rp[k * NN + node] = base + rowOff[i];
    }

    for (int i = t; i < n; i += 256) {
        ull en = __builtin_nontemporal_load(&src[i]);
        uint w0 = (uint)en;
        int local; uint off4;
        if (isU) { local = (int)(w0 >> 16); off4 = (w0 & 0xFFFF) * (TMPW * 2); }
        else     { local = (int)(w0 >> 17); off4 = (w0 & 0x1FFFF) * (TMPW * 2); }
        int p = atomicAdd(&cnt[local], 1);
        stage[p] = (en & 0xFFFFFFFF00000000ull) | off4;
    }
    __syncthreads();

    ull* dst = (isU ? eU : eV) + base;
    for (int i = t; i < n; i += 256)
        __builtin_nontemporal_store(stage[i], &dst[i]);
}

// ---------------------------------------------------------------------------
// Merged-support CSR aggregation helper: ONE wave per node, supports
// [K0,K0+NK) in one interleaved latency chain. NT edge loads (stream-once).
template<int K0, int NK, int B, int NNODE>
__device__ __forceinline__ void agg_do(
    const int* __restrict__ rowPtr, const ull* __restrict__ eArr,
    const char* __restrict__ tSrc, int n, uint lane4,
    float* __restrict__ a0, float* __restrict__ a1)
{
    int s[NK], d[NK];
    #pragma unroll
    for (int kk = 0; kk < NK; ++kk) {
        int g = (K0 + kk) * NNODE + n;
        int ss = rowPtr[g];
        int ee = rowPtr[g + 1];     // sentinel covers the last segment
        s[kk] = ss; d[kk] = ee - ss;
    }
    uint ex[NK][B], ev[NK][B], gw[NK][B];
    #pragma unroll
    for (int kk = 0; kk < NK; ++kk)
        #pragma unroll
        for (int i = 0; i < B; ++i) {
            int idx = (i < d[kk]) ? i : 0;
            ull t = __builtin_nontemporal_load(&eArr[s[kk] + idx]);
            ex[kk][i] = (i < d[kk]) ? (uint)t : 0u;
            ev[kk][i] = (uint)(t >> 32);
        }
    #pragma unroll
    for (int kk = 0; kk < NK; ++kk)
        #pragma unroll
        for (int i = 0; i < B; ++i)
            gw[kk][i] = *(const uint*)(tSrc + (ex[kk][i] + lane4 + ((uint)(K0 + kk) << 8)));
    #pragma unroll
    for (int kk = 0; kk < NK; ++kk) {
        float x0 = 0.f, x1 = 0.f;
        #pragma unroll
        for (int i = 0; i < B; ++i)
            if (i < d[kk]) {
                float v = __uint_as_float(ev[kk][i]);
                x0 = fmaf(v, lof(gw[kk][i]), x0);
                x1 = fmaf(v, hif(gw[kk][i]), x1);
            }
        a0[K0 + kk] = x0; a1[K0 + kk] = x1;
    }
    #pragma unroll
    for (int kk = 0; kk < NK; ++kk) {
        if (d[kk] > B) {            // wave-uniform branch
            uint fx[B], fv[B], g1[B];
            #pragma unroll
            for (int i = 0; i < B; ++i) {
                int idx = (B + i < d[kk]) ? B + i : B;
                ull t = __builtin_nontemporal_load(&eArr[s[kk] + idx]);
                fx[i] = (B + i < d[kk]) ? (uint)t : 0u;
                fv[i] = (uint)(t >> 32);
            }
            #pragma unroll
            for (int i = 0; i < B; ++i)
                g1[i] = *(const uint*)(tSrc + (fx[i] + lane4 + ((uint)(K0 + kk) << 8)));
            #pragma unroll
            for (int i = 0; i < B; ++i)
                if (B + i < d[kk]) {
                    float v = __uint_as_float(fv[i]);
                    a0[K0 + kk] = fmaf(v, lof(g1[i]), a0[K0 + kk]);
                    a1[K0 + kk] = fmaf(v, hif(g1[i]), a1[K0 + kk]);
                }
            for (int p = 2 * B; p < d[kk]; ++p) {
                ull t = __builtin_nontemporal_load(&eArr[s[kk] + p]);
                uint g = *(const uint*)(tSrc + ((uint)t + lane4 + ((uint)(K0 + kk) << 8)));
                float v = __uint_as_float((uint)(t >> 32));
                a0[K0 + kk] = fmaf(v, lof(g), a0[K0 + kk]);
                a1[K0 + kk] = fmaf(v, hif(g), a1[K0 + kk]);
            }
        }
    }
}

__device__ __forceinline__ void agg_store(ushort* Xrow, int lane,
                                          const float* a0, const float* a1) {
    #pragma unroll
    for (int k = 0; k < KSUP; ++k) {
        uint payload = (uint)f2bf(fmaxf(a0[k], 0.f)) |
                       ((uint)f2bf(fmaxf(a1[k], 0.f)) << 16);
        if (lane < 50)
            __builtin_nontemporal_store(payload, (uint*)(Xrow + k * FSUP) + lane);
    }
    if (lane < 6)
        __builtin_nontemporal_store(0u, (uint*)(Xrow + 564) + lane);
}

// U-direction: gathers tmpV
__global__ __launch_bounds__(256) void agg_u_k(
    const int* __restrict__ rowPtrU, const ull* __restrict__ eU,
    const ushort* __restrict__ tmpV, ushort* __restrict__ Xu)
{
    const int lane = threadIdx.x & 63;
    const int n = blockIdx.x * 4 + (threadIdx.x >> 6);
    const uint lane4 = (uint)(((lane < 50) ? lane : 49) << 2);
    float a0[KSUP], a1[KSUP];
    agg_do<0, KSUP, 4, NU>(rowPtrU, eU, (const char*)tmpV, n, lane4, a0, a1);
    agg_store(Xu + (size_t)n * XW, lane, a0, a1);
}

// V-direction: gathers tmpU
__global__ __launch_bounds__(256) void agg_v_k(
    const int* __restrict__ rowPtrV, const ull* __restrict__ eV,
    const ushort* __restrict__ tmpU, ushort* __restrict__ Xv)
{
    const int lane = threadIdx.x & 63;
    const int n = blockIdx.x * 4 + (threadIdx.x >> 6);
    const uint lane4 = (uint)(((lane < 50) ? lane : 49) << 2);
    float a0[KSUP], a1[KSUP];
    agg_do<0, 3, 8, NV>(rowPtrV, eV, (const char*)tmpU, n, lane4, a0, a1);
    agg_do<3, 2, 8, NV>(rowPtrV, eV, (const char*)tmpU, n, lane4, a0, a1);
    agg_store(Xv + (size_t)n * XW, lane, a0, a1);
}

// ---------------------------------------------------------------------------
// final decoder: int2 gathers; basis[b] = dot(embU[u], Vb[v][b]); out=basis@cls
__global__ __launch_bounds__(256) void dec_k(
    const int* __restrict__ ue, const int* __restrict__ ie,
    const ushort* __restrict__ embU, const ushort* __restrict__ Vb,
    const float* __restrict__ cls, float* __restrict__ out, int nE)
{
    int e = blockIdx.x * 8 + (threadIdx.x >> 5);
    if (e >= nE) return;
    int lane = threadIdx.x & 31;
    int u = ue[e], v = ie[e];
    const int2* pu2 = (const int2*)(embU + (size_t)u * DENC);        // 32 int2
    const int2* pv2 = (const int2*)(Vb + (size_t)v * (NBAS * DENC)); // 96 int2
    int2 uu = pu2[lane];                 // cols 4l..4l+3
    int2 bb[NBAS];
    #pragma unroll
    for (int b = 0; b < NBAS; ++b) bb[b] = pv2[b * 32 + lane];
    float uxl = lof((uint)uu.x), uxh = hif((uint)uu.x);
    float uyl = lof((uint)uu.y), uyh = hif((uint)uu.y);
    float s[NBAS];
    #pragma unroll
    for (int b = 0; b < NBAS; ++b) {
        float t = lof((uint)bb[b].x) * uxl;
        t = fmaf(hif((uint)bb[b].x), uxh, t);
        t = fmaf(lof((uint)bb[b].y), uyl, t);
        s[b] = fmaf(hif((uint)bb[b].y), uyh, t);
    }
    #pragma unroll
    for (int off = 16; off; off >>= 1)
        #pragma unroll
        for (int b = 0; b < NBAS; ++b) s[b] += __shfl_xor(s[b], off, 32);
    if (lane < NCLS) {
        float o = 0.f;
        #pragma unroll
        for (int b = 0; b < NBAS; ++b) o += s[b] * cls[b * NCLS + lane];
        out[(size_t)e * NCLS + lane] = o;
    }
}

// ---------------------------------------------------------------------------
extern "C" void kernel_launch(void* const* d_in, const int* in_sizes, int n_in,
                              void* d_out, int out_size, void* d_ws, size_t ws_size,
                              hipStream_t stream) {
    const int*   sup_u  = (const int*)  d_in[0];
    const int*   sup_i  = (const int*)  d_in[1];
    const float* sup_v  = (const float*)d_in[2];
    const float* u_in   = (const float*)d_in[3];
    const float* v_in   = (const float*)d_in[4];
    const float* u_side = (const float*)d_in[5];
    const float* v_side = (const float*)d_in[6];
    const int*   ue     = (const int*)  d_in[7];
    const int*   ie     = (const int*)  d_in[8];
    const float* W_enc  = (const float*)d_in[9];
    const float* Wu1    = (const float*)d_in[10];
    const float* bu1    = (const float*)d_in[11];
    const float* Wi1    = (const float*)d_in[12];
    const float* bi1    = (const float*)d_in[13];
    const float* Wu2    = (const float*)d_in[14];
    const float* Wi2    = (const float*)d_in[15];
    const float* dec_W  = (const float*)d_in[16];
    const float* deccls = (const float*)d_in[17];

    char* ws = (char*)d_ws;
    ushort* u_bf   = (ushort*)(ws);
    ushort* v_bf   = (ushort*)(ws + 102400000LL);
    ushort* Xu     = (ushort*)(ws);
    ushort* Xv     = (ushort*)(ws + 115200000LL);
    // CSR @176M (dead after agg); rowPtr regions padded for the +1 sentinel.
    int*    rowPtrU= (int*)(ws + 179000000LL);          // 2M + 4 sentinel
    int*    rowPtrV= (int*)(ws + 181200000LL);          // 1M + 4 sentinel
    int*    bBase  = (int*)(ws + 185780000LL);          // [1470]
    int*    bCnt   = (int*)(ws + 185810000LL);          // [1470] contiguous
    ull*    eU     = (ull*)(ws + 186000000LL);          // [2M] 16M
    ull*    eV     = (ull*)(ws + 202000000LL);          // [2M] 16M ends 218M
    // tmp @220M (dead after agg): tmpU [NU][640] 128M, tmpV [NV][640] 64M
    ushort* tmpU   = (ushort*)(ws + 220000000LL);
    ushort* tmpV   = (ushort*)(ws + 348000000LL);       // ends 412M
    // L1 buckets: overlay on tmp region (dead before encoder GEMMs write tmp)
    ull*    bktU   = (ull*)(ws + 220000000LL);          // 980*2560*8  = 20.1M
    ull*    bktV   = (ull*)(ws + 241000000LL);          // 490*5120*8  = 20.1M
    // post-agg overlays:
    ushort* embUbf = (ushort*)(ws + 176000000LL);       // [NU][128] 25.6M (over CSR)
    ushort* embVbf = (ushort*)(ws + 202000000LL);       // [NV][128] 12.8M (over eV)
    ushort* Vb     = (ushort*)(ws + 220000000LL);       // [NV][384] 38.4M (over tmp)
    // weights @412M:
    ushort* WencT2 = (ushort*)(ws + 412000000LL);       // [640][512] 0.66M
    ushort* W2ufT  = (ushort*)(ws + 413000000LL);       // [128][576] 0.15M
    ushort* W2ifT  = (ushort*)(ws + 413200000LL);       // [128][576] 0.15M
    ushort* decbf  = (ushort*)(ws + 413400000LL);       // [384][128] 0.10M

    dim3 blk(256);

    // ---- phase 1: fused prep (binhist ∥ weight cvts ∥ input cvt) ----
    hipMemsetAsync(bCnt, 0, 8192, stream);              // bucket counters
    prep_k<<<dim3(PTOT), blk, 0, stream>>>(
        sup_u, sup_i, sup_v, bCnt, bktU, bktV,
        W_enc, WencT2, Wu2, Wi2, W2ufT, W2ifT, dec_W, decbf,
        u_in, v_in, u_bf, v_bf);
    bscan_k<<<dim3(1), blk, 0, stream>>>(bCnt, bBase, rowPtrU, rowPtrV);
    scat3_k<<<dim3(NBT), blk, 0, stream>>>(bCnt, bBase, bktU, bktV,
                                           rowPtrU, rowPtrV, eU, eV);

    // ---- phase 2: fused encoder GEMMs (x = col tile fastest -> L3 reuse) ----
    gemm_enc_k<<<dim3(TMPW / 128, GU128 + GV128), blk, 0, stream>>>(
        u_bf, v_bf, WencT2, tmpU, tmpV);

    // ---- phase 3: CSR aggregation, U then V ----
    agg_u_k<<<dim3(NU / 4), blk, 0, stream>>>(rowPtrU, eU, tmpV, Xu);
    agg_v_k<<<dim3(NV / 4), blk, 0, stream>>>(rowPtrV, eV, tmpU, Xv);

    // ---- phase 4: fused side dense -> X cols 500..563 ----
    side_k<<<dim3(GU64 + GV64), blk, 0, stream>>>(
        u_side, v_side, Wu1, bu1, Wi1, bi1, Xu, Xv);

    // ---- phase 5: fused dense2 = X @ W2fT -> emb bf16 ----
    gemm_d2_k<<<dim3(1, GU128 + GV128), blk, 0, stream>>>(
        Xu, Xv, W2ufT, W2ifT, embUbf, embVbf);

    // ---- phase 6: decoder precompute on V side: Vb = embV @ decbf^T ----
    gemm_bf16_k<<<dim3(3, GV128), blk, 0, stream>>>(embVbf, decbf, Vb, NV, 384, 128, 384);

    // ---- phase 7: final decoder over edges ----
    dec_k<<<dim3(NE / 8), blk, 0, stream>>>(ue, ie, embUbf, Vb, deccls, (float*)d_out, NE);
}